// Round 10
// baseline (418.928 us; speedup 1.0000x reference)
//
#include <hip/hip_runtime.h>
#include <hip/hip_bf16.h>

#define N_NODES 50000
#define N_EDGES 800000
#define N_GRAPHS 64
#define IN_DIM 128
#define HID_DIM 256
#define M_PAD 50048   // N_NODES padded to multiple of 64 for GEMM staging

typedef short sh8 __attribute__((ext_vector_type(8)));
typedef float f4 __attribute__((ext_vector_type(4)));
typedef unsigned short us2 __attribute__((ext_vector_type(2)));
typedef unsigned short us4 __attribute__((ext_vector_type(4)));
typedef unsigned short us8 __attribute__((ext_vector_type(8)));

__device__ __forceinline__ unsigned short bf16rne(float f) {
    unsigned int u = __float_as_uint(f);
    return (unsigned short)((u + 0x7FFFu + ((u >> 16) & 1u)) >> 16);
}
__device__ __forceinline__ float bf2f(unsigned short b) {
    return __uint_as_float((unsigned int)b << 16);
}
__device__ __forceinline__ void split_bf16(float f, unsigned short& h, unsigned short& l) {
    unsigned int u = __float_as_uint(f);
    unsigned int hb = (u + 0x7FFFu + ((u >> 16) & 1u)) & 0xFFFF0000u;  // RNE
    h = (unsigned short)(hb >> 16);
    float rest = f - __uint_as_float(hb);
    unsigned int u2 = __float_as_uint(rest);
    l = (unsigned short)((u2 + 0x7FFFu + ((u2 >> 16) & 1u)) >> 16);
}

// ---------------- degree / CSR build ----------------

__global__ void k_deg_count(const int* __restrict__ dst, int* __restrict__ deg) {
    int e = blockIdx.x * blockDim.x + threadIdx.x;
    if (e < N_EDGES) atomicAdd(&deg[dst[e]], 1);
}

#define SCAN_BLK 1024
#define SCAN_NBLK ((N_NODES + SCAN_BLK - 1) / SCAN_BLK)  // 49

__global__ __launch_bounds__(SCAN_BLK)
void k_scan_blk(const int* __restrict__ deg, int* __restrict__ row_start,
                float* __restrict__ dinv, int* __restrict__ blk_tot) {
    __shared__ int tmp[SCAN_BLK];
    int t = threadIdx.x;
    int i = blockIdx.x * SCAN_BLK + t;
    int d = 0;
    if (i < N_NODES) {
        d = deg[i];
        dinv[i] = rsqrtf((float)d + 1.0f);
    }
    tmp[t] = d;
    __syncthreads();
    #pragma unroll
    for (int off = 1; off < SCAN_BLK; off <<= 1) {
        int v = (t >= off) ? tmp[t - off] : 0;
        __syncthreads();
        tmp[t] += v;
        __syncthreads();
    }
    if (i < N_NODES) row_start[i] = tmp[t] - d;
    if (t == SCAN_BLK - 1) blk_tot[blockIdx.x] = tmp[t];
}

__global__ __launch_bounds__(SCAN_BLK)
void k_scan_add(int* __restrict__ row_start, const int* __restrict__ blk_tot) {
    __shared__ int soff;
    int t = threadIdx.x;
    int bid = blockIdx.x;
    if (t < 64) {
        int v = (t < bid) ? blk_tot[t] : 0;
        #pragma unroll
        for (int m = 1; m < 64; m <<= 1) v += __shfl_xor(v, m, 64);
        if (t == 0) soff = v;
    }
    __syncthreads();
    int i = bid * SCAN_BLK + t;
    if (i < N_NODES) row_start[i] += soff;
    if (bid == 0 && t == 0) row_start[N_NODES] = N_EDGES;
}

__global__ void k_csr_fill(const int* __restrict__ src, const int* __restrict__ dst,
                           const int* __restrict__ row_start, int* __restrict__ cursor,
                           int* __restrict__ col) {
    int e = blockIdx.x * blockDim.x + threadIdx.x;
    if (e < N_EDGES) {
        int d = dst[e];
        int pos = atomicAdd(&cursor[d], 1);
        col[row_start[d] + pos] = src[e];
    }
}

// ---------------- input conversions ----------------

__global__ void k_x2bf(const float* __restrict__ x, unsigned short* __restrict__ xb) {
    int i = blockIdx.x * blockDim.x + threadIdx.x;
    if (i >= N_NODES * IN_DIM / 4) return;
    float4 v = ((const float4*)x)[i];
    us4 o;
    o.x = bf16rne(v.x); o.y = bf16rne(v.y); o.z = bf16rne(v.z); o.w = bf16rne(v.w);
    ((us4*)xb)[i] = o;
}

// Pre-split W[K x 256] into hi/lo global images in fragment-major layout
__global__ void k_wsplit(const float* __restrict__ W, unsigned short* __restrict__ Bh,
                         unsigned short* __restrict__ Bl, int K) {
    int i = blockIdx.x * blockDim.x + threadIdx.x;
    if (i >= K * 256) return;
    int k = i >> 8, c = i & 255;
    unsigned short h, l;
    split_bf16(W[i], h, l);
    size_t pos = (size_t)(k >> 5) * 8192 + (size_t)(((c >> 4) * 4 + ((k >> 3) & 3)) * 128 + (c & 15) * 8 + (k & 7));
    Bh[pos] = h;
    Bl[pos] = l;
}

// ---------------- MFMA GEMM: [M,256] = epilogue(A[M,K] @ B[K,256]) --------
// A pre-split into hi/lo bf16 row-major planes (padded to M_PAD rows).
// 64x256 tile per block, 4 waves, K-step 32, 3-pass hi/lo MFMA.
// MODE 0: Yb = bf16(acc * dinv[m]);  MODE 1: (Ch,Cl) = split(relu(acc + bias[c]))

template<int MODE>
__global__ __launch_bounds__(256)
void k_gemm_mfma(const unsigned short* __restrict__ Ah, const unsigned short* __restrict__ Al,
                 const unsigned short* __restrict__ Bh, const unsigned short* __restrict__ Bl,
                 const float* __restrict__ dinv, const float* __restrict__ bias,
                 unsigned short* __restrict__ Ch, unsigned short* __restrict__ Cl,
                 unsigned short* __restrict__ Yb, int M, int K) {
    __shared__ unsigned short AhL[2048], AlL[2048];
    __shared__ unsigned short BhL[8192], BlL[8192];

    const int tid = threadIdx.x;
    const int wv = tid >> 6, lane = tid & 63;
    const int m0 = blockIdx.x * 64;

    const int ar = wv * 16 + (lane & 15);
    const int kseg = lane >> 4;
    const unsigned short* aph = Ah + (size_t)(m0 + ar) * K + kseg * 8;
    const unsigned short* apl = Al + (size_t)(m0 + ar) * K + kseg * 8;
    const int aslot = wv * 64 + kseg * 16 + (lane & 15);  // units of 8 shorts

    f4 acc[4][4];
    #pragma unroll
    for (int mi = 0; mi < 4; ++mi)
        #pragma unroll
        for (int nj = 0; nj < 4; ++nj)
            acc[mi][nj] = f4{0.f, 0.f, 0.f, 0.f};

    const int nsteps = K >> 5;
    for (int s = 0; s < nsteps; ++s) {
        us8 ah = *reinterpret_cast<const us8*>(aph + s * 32);
        us8 al = *reinterpret_cast<const us8*>(apl + s * 32);
        us8 bh[4], bl[4];
        {
            const unsigned short* gb = Bh + (size_t)s * 8192;
            const unsigned short* gl = Bl + (size_t)s * 8192;
            #pragma unroll
            for (int j = 0; j < 4; ++j) {
                bh[j] = *reinterpret_cast<const us8*>(gb + j * 2048 + tid * 8);
                bl[j] = *reinterpret_cast<const us8*>(gl + j * 2048 + tid * 8);
            }
        }
        __syncthreads();  // prior iteration's LDS reads complete
        *reinterpret_cast<us8*>(&AhL[aslot * 8]) = ah;
        *reinterpret_cast<us8*>(&AlL[aslot * 8]) = al;
        #pragma unroll
        for (int j = 0; j < 4; ++j) {
            *reinterpret_cast<us8*>(&BhL[j * 2048 + tid * 8]) = bh[j];
            *reinterpret_cast<us8*>(&BlL[j * 2048 + tid * 8]) = bl[j];
        }
        __syncthreads();

        sh8 afh[4], afl[4], bfh[4], bfl[4];
        #pragma unroll
        for (int mi = 0; mi < 4; ++mi) {
            afh[mi] = *reinterpret_cast<const sh8*>(&AhL[mi * 512 + lane * 8]);
            afl[mi] = *reinterpret_cast<const sh8*>(&AlL[mi * 512 + lane * 8]);
        }
        #pragma unroll
        for (int nj = 0; nj < 4; ++nj) {
            bfh[nj] = *reinterpret_cast<const sh8*>(&BhL[(wv * 4 + nj) * 512 + lane * 8]);
            bfl[nj] = *reinterpret_cast<const sh8*>(&BlL[(wv * 4 + nj) * 512 + lane * 8]);
        }
        #pragma unroll
        for (int mi = 0; mi < 4; ++mi) {
            #pragma unroll
            for (int nj = 0; nj < 4; ++nj) {
                acc[mi][nj] = __builtin_amdgcn_mfma_f32_16x16x32_bf16(afh[mi], bfh[nj], acc[mi][nj], 0, 0, 0);
                acc[mi][nj] = __builtin_amdgcn_mfma_f32_16x16x32_bf16(afh[mi], bfl[nj], acc[mi][nj], 0, 0, 0);
                acc[mi][nj] = __builtin_amdgcn_mfma_f32_16x16x32_bf16(afl[mi], bfh[nj], acc[mi][nj], 0, 0, 0);
            }
        }
    }

    #pragma unroll
    for (int mi = 0; mi < 4; ++mi) {
        #pragma unroll
        for (int q = 0; q < 4; ++q) {
            int grow = m0 + mi * 16 + (lane >> 4) * 4 + q;
            if (grow < M) {
                float dm = (MODE == 0) ? dinv[grow] : 0.f;
                #pragma unroll
                for (int nj = 0; nj < 4; ++nj) {
                    int gcol = wv * 64 + nj * 16 + (lane & 15);
                    float v = acc[mi][nj][q];
                    if (MODE == 0) {
                        Yb[(size_t)grow * 256 + gcol] = bf16rne(v * dm);
                    } else {
                        float r = fmaxf(v + bias[gcol], 0.f);
                        unsigned short h, l;
                        split_bf16(r, h, l);
                        Ch[(size_t)grow * 256 + gcol] = h;
                        Cl[(size_t)grow * 256 + gcol] = l;
                    }
                }
            }
        }
    }
}

// ---------------- aggregation (feature-partitioned, XCD-affine) ----------------
// Wave = 4 subgroups x 16 lanes; one VMEM instr gathers 4 edges' 64B segments.
// blockIdx % GROUPS = channel group; round-robin dispatch pins group -> XCD,
// so each XCD's L2 only holds its 3.2 MB channel slice of the gather plane.

// layer-1: z[n] = dinv[n]*(dinv[n]*x[n] + sum dinv[s]*xb[s]); hi/lo split output.
// 4 groups x 32 channels (of 128). 32 nodes per block (4 waves x 8).
__global__ __launch_bounds__(256)
void k_agg_x(const float* __restrict__ x, const unsigned short* __restrict__ xb,
             const int* __restrict__ row_start, const int* __restrict__ col,
             const float* __restrict__ dinv,
             unsigned short* __restrict__ zh, unsigned short* __restrict__ zl) {
    const int tid = threadIdx.x;
    const int wv = tid >> 6, lane = tid & 63;
    const int sg = lane >> 4, cl = lane & 15;
    const int g = blockIdx.x & 3;
    const int n0 = (blockIdx.x >> 2) * 32 + wv * 8;

    const unsigned short* segx = xb + g * 32 + cl * 2;

    for (int i = 0; i < 8; ++i) {
        int n = n0 + i;
        if (n >= N_NODES) break;
        int e0 = row_start[n], e1 = row_start[n + 1];
        float a0 = 0.f, a1 = 0.f;
        int e = e0 + sg;
        for (; e + 4 < e1; e += 8) {
            int s0 = col[e], s1 = col[e + 4];
            float d0 = dinv[s0], d1 = dinv[s1];
            us2 v0 = *reinterpret_cast<const us2*>(segx + (size_t)s0 * 128);
            us2 v1 = *reinterpret_cast<const us2*>(segx + (size_t)s1 * 128);
            a0 += bf2f(v0.x) * d0 + bf2f(v1.x) * d1;
            a1 += bf2f(v0.y) * d0 + bf2f(v1.y) * d1;
        }
        for (; e < e1; e += 4) {
            int s = col[e];
            float ds = dinv[s];
            us2 v = *reinterpret_cast<const us2*>(segx + (size_t)s * 128);
            a0 += bf2f(v.x) * ds;
            a1 += bf2f(v.y) * ds;
        }
        a0 += __shfl_xor(a0, 16, 64); a0 += __shfl_xor(a0, 32, 64);
        a1 += __shfl_xor(a1, 16, 64); a1 += __shfl_xor(a1, 32, 64);
        float dn = dinv[n];
        float2 xs = *reinterpret_cast<const float2*>(x + (size_t)n * 128 + g * 32 + cl * 2);
        a0 = (a0 + xs.x * dn) * dn;
        a1 = (a1 + xs.y * dn) * dn;
        if (lane < 16) {
            unsigned short h0, l0, h1, l1;
            split_bf16(a0, h0, l0);
            split_bf16(a1, h1, l1);
            us2 vh, vl;
            vh.x = h0; vh.y = h1;
            vl.x = l0; vl.y = l1;
            *reinterpret_cast<us2*>(zh + (size_t)n * 128 + g * 32 + cl * 2) = vh;
            *reinterpret_cast<us2*>(zl + (size_t)n * 128 + g * 32 + cl * 2) = vl;
        }
    }
}

// layer-2 agg + relu + mean-pool fused. yb pre-scaled by dinv[src] (bf16).
// 8 groups x 32 channels (of 256). 32 nodes per block (4 waves x 8).
// Pool accumulates in registers; flush on graph change (no LDS).
__global__ __launch_bounds__(256)
void k_agg_pool(const unsigned short* __restrict__ yb, const int* __restrict__ row_start,
                const int* __restrict__ col, const float* __restrict__ dinv,
                const float* __restrict__ bias, const int* __restrict__ batch,
                float* __restrict__ sums) {
    const int tid = threadIdx.x;
    const int wv = tid >> 6, lane = tid & 63;
    const int sg = lane >> 4, cl = lane & 15;
    const int g = blockIdx.x & 7;
    const int n0 = (blockIdx.x >> 3) * 32 + wv * 8;

    const int ch = g * 32 + cl * 2;
    const float b0 = bias[ch], b1 = bias[ch + 1];
    const unsigned short* seg = yb + g * 32 + cl * 2;

    float p0 = 0.f, p1 = 0.f;
    int cur_g = batch[n0 < N_NODES ? n0 : N_NODES - 1];

    for (int i = 0; i < 8; ++i) {
        int n = n0 + i;
        if (n >= N_NODES) break;
        int e0 = row_start[n], e1 = row_start[n + 1];
        float a0 = 0.f, a1 = 0.f;
        int e = e0 + sg;
        for (; e + 4 < e1; e += 8) {
            int s0 = col[e], s1 = col[e + 4];
            us2 v0 = *reinterpret_cast<const us2*>(seg + (size_t)s0 * 256);
            us2 v1 = *reinterpret_cast<const us2*>(seg + (size_t)s1 * 256);
            a0 += bf2f(v0.x) + bf2f(v1.x);
            a1 += bf2f(v0.y) + bf2f(v1.y);
        }
        for (; e < e1; e += 4) {
            int s = col[e];
            us2 v = *reinterpret_cast<const us2*>(seg + (size_t)s * 256);
            a0 += bf2f(v.x);
            a1 += bf2f(v.y);
        }
        a0 += __shfl_xor(a0, 16, 64); a0 += __shfl_xor(a0, 32, 64);
        a1 += __shfl_xor(a1, 16, 64); a1 += __shfl_xor(a1, 32, 64);
        // self term (added once, after subgroup reduction)
        us2 sv = *reinterpret_cast<const us2*>(seg + (size_t)n * 256);
        a0 += bf2f(sv.x);
        a1 += bf2f(sv.y);
        float dn = dinv[n];
        float o0 = fmaxf(a0 * dn + b0, 0.f);
        float o1 = fmaxf(a1 * dn + b1, 0.f);
        int gn = batch[n];
        if (gn != cur_g) {
            if (lane < 16) {
                atomicAdd(&sums[cur_g * 256 + ch], p0);
                atomicAdd(&sums[cur_g * 256 + ch + 1], p1);
            }
            p0 = 0.f; p1 = 0.f;
            cur_g = gn;
        }
        p0 += o0;
        p1 += o1;
    }
    if (lane < 16) {
        atomicAdd(&sums[cur_g * 256 + ch], p0);
        atomicAdd(&sums[cur_g * 256 + ch + 1], p1);
    }
}

// ---------------- bounds + sums-init + FC ----------------

__global__ __launch_bounds__(512)
void k_bounds_init(const int* __restrict__ batch, int* __restrict__ bounds,
                   float* __restrict__ sums) {
    int t = threadIdx.x;
    if (t <= N_GRAPHS) {
        int lo = 0, hi = N_NODES;
        while (lo < hi) {
            int mid = (lo + hi) >> 1;
            if (batch[mid] < t) lo = mid + 1; else hi = mid;
        }
        bounds[t] = lo;
    }
    for (int i = t; i < N_GRAPHS * HID_DIM; i += 512) sums[i] = 0.f;
}

__global__ void k_final(const float* __restrict__ sums, const int* __restrict__ bounds,
                        const float* __restrict__ Wfc, const float* __restrict__ bfc,
                        float* __restrict__ out) {
    __shared__ float red[HID_DIM];
    int g = blockIdx.x;
    int c = threadIdx.x;
    float cnt = (float)(bounds[g + 1] - bounds[g]);
    float v = sums[g * HID_DIM + c] / fmaxf(cnt, 1.0f) * Wfc[c];
    red[c] = v;
    __syncthreads();
    for (int s = HID_DIM / 2; s > 0; s >>= 1) {
        if (c < s) red[c] += red[c + s];
        __syncthreads();
    }
    if (c == 0) out[g] = red[0] + bfc[0];
}

// ---------------- launch ----------------

extern "C" void kernel_launch(void* const* d_in, const int* in_sizes, int n_in,
                              void* d_out, int out_size, void* d_ws, size_t ws_size,
                              hipStream_t stream) {
    const float* x    = (const float*)d_in[0];
    const int*   ei   = (const int*)d_in[1];
    const int*   batch= (const int*)d_in[2];
    const float* W1   = (const float*)d_in[3];
    const float* b1   = (const float*)d_in[4];
    const float* W2   = (const float*)d_in[5];
    const float* b2   = (const float*)d_in[6];
    const float* Wfc  = (const float*)d_in[7];
    const float* bfc  = (const float*)d_in[8];
    float* out = (float*)d_out;

    const int* src = ei;
    const int* dst = ei + N_EDGES;

    char* ws = (char*)d_ws;
    const size_t PLANE256 = (size_t)M_PAD * 256 * 2;
    const size_t PLANE128 = (size_t)M_PAD * 128 * 2;
    size_t off = 0;
    unsigned short* h1h = (unsigned short*)(ws + off); off += PLANE256;
    unsigned short* h1l = (unsigned short*)(ws + off); off += PLANE256;
    unsigned short* zh  = (unsigned short*)(ws + off); off += PLANE128;  // y2b overlays zh+zl
    unsigned short* zl  = (unsigned short*)(ws + off); off += PLANE128;
    unsigned short* xb  = (unsigned short*)(ws + off); off += (size_t)N_NODES * 128 * 2;
    int*   deg_i     = (int*)  (ws + off); off += 200704;
    int*   cursor    = (int*)  (ws + off); off += 200704;
    float* dinv      = (float*)(ws + off); off += 200704;
    int*   row_start = (int*)  (ws + off); off += 200704;
    int*   col       = (int*)  (ws + off); off += (size_t)N_EDGES * 4;
    unsigned short* Bh1 = (unsigned short*)(ws + off); off += 65536;
    unsigned short* Bl1 = (unsigned short*)(ws + off); off += 65536;
    unsigned short* Bh2 = (unsigned short*)(ws + off); off += 131072;
    unsigned short* Bl2 = (unsigned short*)(ws + off); off += 131072;
    float* sums      = (float*)(ws + off); off += 65536;
    int*   bounds    = (int*)  (ws + off); off += 512;
    int*   blk_tot   = (int*)  (ws + off); off += 512;
    (void)ws_size; (void)in_sizes; (void)n_in; (void)out_size;

    unsigned short* y2b = zh;  // z planes dead after GEMM1

    // 1. CSR build + dinv + weight split + x->bf16
    hipMemsetAsync(deg_i, 0, 2 * 200704, stream);
    k_deg_count<<<(N_EDGES + 255) / 256, 256, 0, stream>>>(dst, deg_i);
    k_scan_blk<<<SCAN_NBLK, SCAN_BLK, 0, stream>>>(deg_i, row_start, dinv, blk_tot);
    k_scan_add<<<SCAN_NBLK, SCAN_BLK, 0, stream>>>(row_start, blk_tot);
    k_csr_fill<<<(N_EDGES + 255) / 256, 256, 0, stream>>>(src, dst, row_start, cursor, col);
    k_x2bf<<<(N_NODES * IN_DIM / 4 + 255) / 256, 256, 0, stream>>>(x, xb);
    k_wsplit<<<(IN_DIM * 256 + 255) / 256, 256, 0, stream>>>(W1, Bh1, Bl1, IN_DIM);
    k_wsplit<<<(HID_DIM * 256 + 255) / 256, 256, 0, stream>>>(W2, Bh2, Bl2, HID_DIM);
    k_bounds_init<<<1, 512, 0, stream>>>(batch, bounds, sums);

    const int gemm_grid = (N_NODES + 63) / 64;  // 782
    const int nchunks = (N_NODES + 31) / 32;    // 1563

    // 2. layer 1: (zh,zl) = split(A_hat @ x) ; (h1h,h1l) = split(relu(z @ W1 + b1))
    k_agg_x<<<nchunks * 4, 256, 0, stream>>>(x, xb, row_start, col, dinv, zh, zl);
    k_gemm_mfma<1><<<gemm_grid, 256, 0, stream>>>(zh, zl, Bh1, Bl1, dinv, b1, h1h, h1l, nullptr, N_NODES, IN_DIM);

    // 3. layer 2: y2b = bf16((h1 @ W2) * dinv) ; fused agg+relu+pool (XCD-affine)
    k_gemm_mfma<0><<<gemm_grid, 256, 0, stream>>>(h1h, h1l, Bh2, Bl2, dinv, b2, nullptr, nullptr, y2b, N_NODES, HID_DIM);
    k_agg_pool<<<nchunks * 8, 256, 0, stream>>>(y2b, row_start, col, dinv, b2, batch, sums);

    // 4. fc
    k_final<<<N_GRAPHS, HID_DIM, 0, stream>>>(sums, bounds, Wfc, bfc, out);
}

// Round 11
// 281.005 us; speedup vs baseline: 1.4908x; 1.4908x over previous
//
#include <hip/hip_runtime.h>
#include <hip/hip_bf16.h>

#define N_NODES 50000
#define N_EDGES 800000
#define N_GRAPHS 64
#define IN_DIM 128
#define HID_DIM 256
#define M_PAD 50048   // N_NODES padded to multiple of 64 for GEMM staging

typedef short sh8 __attribute__((ext_vector_type(8)));
typedef float f4 __attribute__((ext_vector_type(4)));
typedef unsigned short us4 __attribute__((ext_vector_type(4)));
typedef unsigned short us8 __attribute__((ext_vector_type(8)));

__device__ __forceinline__ unsigned short bf16rne(float f) {
    unsigned int u = __float_as_uint(f);
    return (unsigned short)((u + 0x7FFFu + ((u >> 16) & 1u)) >> 16);
}
__device__ __forceinline__ float bf2f(unsigned short b) {
    return __uint_as_float((unsigned int)b << 16);
}
__device__ __forceinline__ void split_bf16(float f, unsigned short& h, unsigned short& l) {
    unsigned int u = __float_as_uint(f);
    unsigned int hb = (u + 0x7FFFu + ((u >> 16) & 1u)) & 0xFFFF0000u;  // RNE
    h = (unsigned short)(hb >> 16);
    float rest = f - __uint_as_float(hb);
    unsigned int u2 = __float_as_uint(rest);
    l = (unsigned short)((u2 + 0x7FFFu + ((u2 >> 16) & 1u)) >> 16);
}

// async 16B global -> LDS (direct, no VGPR round-trip)
__device__ __forceinline__ void gl2lds16(const unsigned short* g, unsigned short* l) {
    __builtin_amdgcn_global_load_lds(
        (const __attribute__((address_space(1))) void*)g,
        (__attribute__((address_space(3))) void*)l, 16, 0, 0);
}

// ---------------- degree / CSR build ----------------

__global__ void k_deg_count(const int* __restrict__ dst, int* __restrict__ deg) {
    int e = blockIdx.x * blockDim.x + threadIdx.x;
    if (e < N_EDGES) atomicAdd(&deg[dst[e]], 1);
}

#define SCAN_BLK 1024
#define SCAN_NBLK ((N_NODES + SCAN_BLK - 1) / SCAN_BLK)  // 49

__global__ __launch_bounds__(SCAN_BLK)
void k_scan_blk(const int* __restrict__ deg, int* __restrict__ row_start,
                float* __restrict__ dinv, int* __restrict__ blk_tot) {
    __shared__ int tmp[SCAN_BLK];
    int t = threadIdx.x;
    int i = blockIdx.x * SCAN_BLK + t;
    int d = 0;
    if (i < N_NODES) {
        d = deg[i];
        dinv[i] = rsqrtf((float)d + 1.0f);
    }
    tmp[t] = d;
    __syncthreads();
    #pragma unroll
    for (int off = 1; off < SCAN_BLK; off <<= 1) {
        int v = (t >= off) ? tmp[t - off] : 0;
        __syncthreads();
        tmp[t] += v;
        __syncthreads();
    }
    if (i < N_NODES) row_start[i] = tmp[t] - d;
    if (t == SCAN_BLK - 1) blk_tot[blockIdx.x] = tmp[t];
}

__global__ __launch_bounds__(SCAN_BLK)
void k_scan_add(int* __restrict__ row_start, const int* __restrict__ blk_tot) {
    __shared__ int soff;
    int t = threadIdx.x;
    int bid = blockIdx.x;
    if (t < 64) {
        int v = (t < bid) ? blk_tot[t] : 0;
        #pragma unroll
        for (int m = 1; m < 64; m <<= 1) v += __shfl_xor(v, m, 64);
        if (t == 0) soff = v;
    }
    __syncthreads();
    int i = bid * SCAN_BLK + t;
    if (i < N_NODES) row_start[i] += soff;
    if (bid == 0 && t == 0) row_start[N_NODES] = N_EDGES;
}

__global__ void k_csr_fill(const int* __restrict__ src, const int* __restrict__ dst,
                           const int* __restrict__ row_start, int* __restrict__ cursor,
                           int* __restrict__ col) {
    int e = blockIdx.x * blockDim.x + threadIdx.x;
    if (e < N_EDGES) {
        int d = dst[e];
        int pos = atomicAdd(&cursor[d], 1);
        col[row_start[d] + pos] = src[e];
    }
}

// ---------------- input conversions ----------------

__global__ void k_x2bf(const float* __restrict__ x, unsigned short* __restrict__ xb) {
    int i = blockIdx.x * blockDim.x + threadIdx.x;
    if (i >= N_NODES * IN_DIM / 4) return;
    float4 v = ((const float4*)x)[i];
    us4 o;
    o.x = bf16rne(v.x); o.y = bf16rne(v.y); o.z = bf16rne(v.z); o.w = bf16rne(v.w);
    ((us4*)xb)[i] = o;
}

// Pre-split W[K x 256] into hi/lo global images in fragment-major layout
__global__ void k_wsplit(const float* __restrict__ W, unsigned short* __restrict__ Bh,
                         unsigned short* __restrict__ Bl, int K) {
    int i = blockIdx.x * blockDim.x + threadIdx.x;
    if (i >= K * 256) return;
    int k = i >> 8, c = i & 255;
    unsigned short h, l;
    split_bf16(W[i], h, l);
    size_t pos = (size_t)(k >> 5) * 8192 + (size_t)(((c >> 4) * 4 + ((k >> 3) & 3)) * 128 + (c & 15) * 8 + (k & 7));
    Bh[pos] = h;
    Bl[pos] = l;
}

// ---------------- MFMA GEMM: [M,256] = epilogue(A[M,K] @ B[K,256]) --------
// A pre-split into hi/lo bf16 row-major planes (padded to M_PAD rows).
// 64x256 tile per block, 4 waves, K-step 32, 3-pass hi/lo MFMA.
// Staging via global_load_lds width=16 (dest = wave base + lane*16B).
// MODE 0: Yb = bf16(acc * dinv[m]);  MODE 1: (Ch,Cl) = split(relu(acc + bias[c]))

template<int MODE>
__global__ __launch_bounds__(256)
void k_gemm_mfma(const unsigned short* __restrict__ Ah, const unsigned short* __restrict__ Al,
                 const unsigned short* __restrict__ Bh, const unsigned short* __restrict__ Bl,
                 const float* __restrict__ dinv, const float* __restrict__ bias,
                 unsigned short* __restrict__ Ch, unsigned short* __restrict__ Cl,
                 unsigned short* __restrict__ Yb, int M, int K) {
    __shared__ unsigned short AhL[2048], AlL[2048];
    __shared__ unsigned short BhL[8192], BlL[8192];

    const int tid = threadIdx.x;
    const int wv = tid >> 6, lane = tid & 63;
    const int m0 = blockIdx.x * 64;

    const int ar = wv * 16 + (lane & 15);
    const int kseg = lane >> 4;
    const unsigned short* aph = Ah + (size_t)(m0 + ar) * K + kseg * 8;
    const unsigned short* apl = Al + (size_t)(m0 + ar) * K + kseg * 8;
    // A dest slot: (wv*64 + kseg*16 + (lane&15)) * 8 shorts == (wv*64+lane)*16B
    unsigned short* adh = &AhL[(wv * 64 + lane) * 8];
    unsigned short* adl = &AlL[(wv * 64 + lane) * 8];

    f4 acc[4][4];
    #pragma unroll
    for (int mi = 0; mi < 4; ++mi)
        #pragma unroll
        for (int nj = 0; nj < 4; ++nj)
            acc[mi][nj] = f4{0.f, 0.f, 0.f, 0.f};

    const int nsteps = K >> 5;
    for (int s = 0; s < nsteps; ++s) {
        __syncthreads();  // prior iteration's LDS reads complete
        gl2lds16(aph + s * 32, adh);
        gl2lds16(apl + s * 32, adl);
        {
            const unsigned short* gb = Bh + (size_t)s * 8192;
            const unsigned short* gl = Bl + (size_t)s * 8192;
            #pragma unroll
            for (int j = 0; j < 4; ++j) {
                gl2lds16(gb + j * 2048 + tid * 8, &BhL[j * 2048 + tid * 8]);
                gl2lds16(gl + j * 2048 + tid * 8, &BlL[j * 2048 + tid * 8]);
            }
        }
        __syncthreads();  // drains vmcnt -> staged data visible

        sh8 afh[4], afl[4], bfh[4], bfl[4];
        #pragma unroll
        for (int mi = 0; mi < 4; ++mi) {
            afh[mi] = *reinterpret_cast<const sh8*>(&AhL[mi * 512 + lane * 8]);
            afl[mi] = *reinterpret_cast<const sh8*>(&AlL[mi * 512 + lane * 8]);
        }
        #pragma unroll
        for (int nj = 0; nj < 4; ++nj) {
            bfh[nj] = *reinterpret_cast<const sh8*>(&BhL[(wv * 4 + nj) * 512 + lane * 8]);
            bfl[nj] = *reinterpret_cast<const sh8*>(&BlL[(wv * 4 + nj) * 512 + lane * 8]);
        }
        #pragma unroll
        for (int mi = 0; mi < 4; ++mi) {
            #pragma unroll
            for (int nj = 0; nj < 4; ++nj) {
                acc[mi][nj] = __builtin_amdgcn_mfma_f32_16x16x32_bf16(afh[mi], bfh[nj], acc[mi][nj], 0, 0, 0);
                acc[mi][nj] = __builtin_amdgcn_mfma_f32_16x16x32_bf16(afh[mi], bfl[nj], acc[mi][nj], 0, 0, 0);
                acc[mi][nj] = __builtin_amdgcn_mfma_f32_16x16x32_bf16(afl[mi], bfh[nj], acc[mi][nj], 0, 0, 0);
            }
        }
    }

    #pragma unroll
    for (int mi = 0; mi < 4; ++mi) {
        #pragma unroll
        for (int q = 0; q < 4; ++q) {
            int grow = m0 + mi * 16 + (lane >> 4) * 4 + q;
            if (grow < M) {
                float dm = (MODE == 0) ? dinv[grow] : 0.f;
                #pragma unroll
                for (int nj = 0; nj < 4; ++nj) {
                    int gcol = wv * 64 + nj * 16 + (lane & 15);
                    float v = acc[mi][nj][q];
                    if (MODE == 0) {
                        Yb[(size_t)grow * 256 + gcol] = bf16rne(v * dm);
                    } else {
                        float r = fmaxf(v + bias[gcol], 0.f);
                        unsigned short h, l;
                        split_bf16(r, h, l);
                        Ch[(size_t)grow * 256 + gcol] = h;
                        Cl[(size_t)grow * 256 + gcol] = l;
                    }
                }
            }
        }
    }
}

// ---------------- aggregation (round-9 proven shapes) ----------------

// layer-1: z[n] = dinv[n] * ( dinv[n]*x[n] + sum dinv[s]*xb[s] )
// Half-wave dual-edge + 4x unroll. Outputs hi/lo planes.
__global__ __launch_bounds__(256)
void k_agg_x(const float* __restrict__ x, const unsigned short* __restrict__ xb,
             const int* __restrict__ row_start, const int* __restrict__ col,
             const float* __restrict__ dinv,
             unsigned short* __restrict__ zh, unsigned short* __restrict__ zl) {
    int wv = threadIdx.x >> 6, lane = threadIdx.x & 63;
    int half = lane >> 5, sub = lane & 31;
    int n = blockIdx.x * 4 + wv;

    float a0 = 0.f, a1 = 0.f, a2 = 0.f, a3 = 0.f;
    float dn = dinv[n];
    if (half == 0) {
        float4 xs = ((const float4*)x)[(size_t)n * 32 + sub];
        a0 = xs.x * dn; a1 = xs.y * dn; a2 = xs.z * dn; a3 = xs.w * dn;
    }
    const us4* xb4 = (const us4*)xb;
    int e = row_start[n] + half;
    const int e1 = row_start[n + 1];
    for (; e + 6 < e1; e += 8) {
        int s0 = col[e], s1 = col[e + 2], s2 = col[e + 4], s3 = col[e + 6];
        float d0 = dinv[s0], d1 = dinv[s1], d2 = dinv[s2], d3 = dinv[s3];
        us4 v0 = xb4[(size_t)s0 * 32 + sub];
        us4 v1 = xb4[(size_t)s1 * 32 + sub];
        us4 v2 = xb4[(size_t)s2 * 32 + sub];
        us4 v3 = xb4[(size_t)s3 * 32 + sub];
        a0 += bf2f(v0.x) * d0 + bf2f(v1.x) * d1 + bf2f(v2.x) * d2 + bf2f(v3.x) * d3;
        a1 += bf2f(v0.y) * d0 + bf2f(v1.y) * d1 + bf2f(v2.y) * d2 + bf2f(v3.y) * d3;
        a2 += bf2f(v0.z) * d0 + bf2f(v1.z) * d1 + bf2f(v2.z) * d2 + bf2f(v3.z) * d3;
        a3 += bf2f(v0.w) * d0 + bf2f(v1.w) * d1 + bf2f(v2.w) * d2 + bf2f(v3.w) * d3;
    }
    for (; e < e1; e += 2) {
        int s = col[e];
        float ds = dinv[s];
        us4 v = xb4[(size_t)s * 32 + sub];
        a0 += bf2f(v.x) * ds; a1 += bf2f(v.y) * ds;
        a2 += bf2f(v.z) * ds; a3 += bf2f(v.w) * ds;
    }
    a0 += __shfl_xor(a0, 32, 64);
    a1 += __shfl_xor(a1, 32, 64);
    a2 += __shfl_xor(a2, 32, 64);
    a3 += __shfl_xor(a3, 32, 64);
    if (half == 0) {
        float o[4] = {a0 * dn, a1 * dn, a2 * dn, a3 * dn};
        us4 oh, ol;
        #pragma unroll
        for (int j = 0; j < 4; ++j) {
            unsigned short h, l;
            split_bf16(o[j], h, l);
            oh[j] = h; ol[j] = l;
        }
        ((us4*)zh)[(size_t)n * 32 + sub] = oh;
        ((us4*)zl)[(size_t)n * 32 + sub] = ol;
    }
}

// layer-2 agg + relu + mean-pool fused. yb pre-scaled by dinv[src] (bf16).
// 8 nodes per 512-thread block. Half-wave dual-edge + 4x unroll.
__global__ __launch_bounds__(512)
void k_agg_pool(const unsigned short* __restrict__ yb, const int* __restrict__ row_start,
                const int* __restrict__ col, const float* __restrict__ dinv,
                const float* __restrict__ bias, const int* __restrict__ batch,
                float* __restrict__ sums) {
    __shared__ float lsum[8][256];
    const int tid = threadIdx.x;
    const int wv = tid >> 6, lane = tid & 63;
    const int half = lane >> 5, sub = lane & 31;
    const int base = blockIdx.x * 8;
    const int n = base + wv;

    const bool uni = (batch[base] == batch[base + 7]);

    const us8* y8 = (const us8*)yb;
    float a[8] = {0.f, 0.f, 0.f, 0.f, 0.f, 0.f, 0.f, 0.f};
    if (half == 0) {
        us8 sv = y8[(size_t)n * 32 + sub];
        #pragma unroll
        for (int j = 0; j < 8; ++j) a[j] = bf2f(sv[j]);
    }
    int e = row_start[n] + half;
    const int e1 = row_start[n + 1];
    for (; e + 6 < e1; e += 8) {
        int s0 = col[e], s1 = col[e + 2], s2 = col[e + 4], s3 = col[e + 6];
        us8 v0 = y8[(size_t)s0 * 32 + sub];
        us8 v1 = y8[(size_t)s1 * 32 + sub];
        us8 v2 = y8[(size_t)s2 * 32 + sub];
        us8 v3 = y8[(size_t)s3 * 32 + sub];
        #pragma unroll
        for (int j = 0; j < 8; ++j)
            a[j] += (bf2f(v0[j]) + bf2f(v1[j])) + (bf2f(v2[j]) + bf2f(v3[j]));
    }
    for (; e < e1; e += 2) {
        int s = col[e];
        us8 v = y8[(size_t)s * 32 + sub];
        #pragma unroll
        for (int j = 0; j < 8; ++j) a[j] += bf2f(v[j]);
    }
    #pragma unroll
    for (int j = 0; j < 8; ++j) a[j] += __shfl_xor(a[j], 32, 64);

    if (half == 0) {
        float dn = dinv[n];
        float4 b0 = ((const float4*)bias)[sub * 2];
        float4 b1 = ((const float4*)bias)[sub * 2 + 1];
        float4 o0, o1;
        o0.x = fmaxf(a[0] * dn + b0.x, 0.f);
        o0.y = fmaxf(a[1] * dn + b0.y, 0.f);
        o0.z = fmaxf(a[2] * dn + b0.z, 0.f);
        o0.w = fmaxf(a[3] * dn + b0.w, 0.f);
        o1.x = fmaxf(a[4] * dn + b1.x, 0.f);
        o1.y = fmaxf(a[5] * dn + b1.y, 0.f);
        o1.z = fmaxf(a[6] * dn + b1.z, 0.f);
        o1.w = fmaxf(a[7] * dn + b1.w, 0.f);
        if (uni) {
            ((float4*)&lsum[wv][sub * 8])[0] = o0;
            ((float4*)&lsum[wv][sub * 8])[1] = o1;
        } else {
            int g = batch[n];
            atomicAdd(&sums[g * 256 + sub * 8 + 0], o0.x);
            atomicAdd(&sums[g * 256 + sub * 8 + 1], o0.y);
            atomicAdd(&sums[g * 256 + sub * 8 + 2], o0.z);
            atomicAdd(&sums[g * 256 + sub * 8 + 3], o0.w);
            atomicAdd(&sums[g * 256 + sub * 8 + 4], o1.x);
            atomicAdd(&sums[g * 256 + sub * 8 + 5], o1.y);
            atomicAdd(&sums[g * 256 + sub * 8 + 6], o1.z);
            atomicAdd(&sums[g * 256 + sub * 8 + 7], o1.w);
        }
    }
    __syncthreads();
    if (uni && tid < 256) {
        float v = 0.f;
        #pragma unroll
        for (int w = 0; w < 8; ++w) v += lsum[w][tid];
        atomicAdd(&sums[batch[base] * 256 + tid], v);
    }
}

// ---------------- bounds + sums-init + FC ----------------

__global__ __launch_bounds__(512)
void k_bounds_init(const int* __restrict__ batch, int* __restrict__ bounds,
                   float* __restrict__ sums) {
    int t = threadIdx.x;
    if (t <= N_GRAPHS) {
        int lo = 0, hi = N_NODES;
        while (lo < hi) {
            int mid = (lo + hi) >> 1;
            if (batch[mid] < t) lo = mid + 1; else hi = mid;
        }
        bounds[t] = lo;
    }
    for (int i = t; i < N_GRAPHS * HID_DIM; i += 512) sums[i] = 0.f;
}

__global__ void k_final(const float* __restrict__ sums, const int* __restrict__ bounds,
                        const float* __restrict__ Wfc, const float* __restrict__ bfc,
                        float* __restrict__ out) {
    __shared__ float red[HID_DIM];
    int g = blockIdx.x;
    int c = threadIdx.x;
    float cnt = (float)(bounds[g + 1] - bounds[g]);
    float v = sums[g * HID_DIM + c] / fmaxf(cnt, 1.0f) * Wfc[c];
    red[c] = v;
    __syncthreads();
    for (int s = HID_DIM / 2; s > 0; s >>= 1) {
        if (c < s) red[c] += red[c + s];
        __syncthreads();
    }
    if (c == 0) out[g] = red[0] + bfc[0];
}

// ---------------- launch ----------------

extern "C" void kernel_launch(void* const* d_in, const int* in_sizes, int n_in,
                              void* d_out, int out_size, void* d_ws, size_t ws_size,
                              hipStream_t stream) {
    const float* x    = (const float*)d_in[0];
    const int*   ei   = (const int*)d_in[1];
    const int*   batch= (const int*)d_in[2];
    const float* W1   = (const float*)d_in[3];
    const float* b1   = (const float*)d_in[4];
    const float* W2   = (const float*)d_in[5];
    const float* b2   = (const float*)d_in[6];
    const float* Wfc  = (const float*)d_in[7];
    const float* bfc  = (const float*)d_in[8];
    float* out = (float*)d_out;

    const int* src = ei;
    const int* dst = ei + N_EDGES;

    char* ws = (char*)d_ws;
    const size_t PLANE256 = (size_t)M_PAD * 256 * 2;
    const size_t PLANE128 = (size_t)M_PAD * 128 * 2;
    size_t off = 0;
    unsigned short* h1h = (unsigned short*)(ws + off); off += PLANE256;
    unsigned short* h1l = (unsigned short*)(ws + off); off += PLANE256;
    unsigned short* zh  = (unsigned short*)(ws + off); off += PLANE128;  // y2b overlays zh+zl
    unsigned short* zl  = (unsigned short*)(ws + off); off += PLANE128;
    unsigned short* xb  = (unsigned short*)(ws + off); off += (size_t)N_NODES * 128 * 2;
    int*   deg_i     = (int*)  (ws + off); off += 200704;
    int*   cursor    = (int*)  (ws + off); off += 200704;
    float* dinv      = (float*)(ws + off); off += 200704;
    int*   row_start = (int*)  (ws + off); off += 200704;
    int*   col       = (int*)  (ws + off); off += (size_t)N_EDGES * 4;
    unsigned short* Bh1 = (unsigned short*)(ws + off); off += 65536;
    unsigned short* Bl1 = (unsigned short*)(ws + off); off += 65536;
    unsigned short* Bh2 = (unsigned short*)(ws + off); off += 131072;
    unsigned short* Bl2 = (unsigned short*)(ws + off); off += 131072;
    float* sums      = (float*)(ws + off); off += 65536;
    int*   bounds    = (int*)  (ws + off); off += 512;
    int*   blk_tot   = (int*)  (ws + off); off += 512;
    (void)ws_size; (void)in_sizes; (void)n_in; (void)out_size;

    unsigned short* y2b = zh;  // z planes dead after GEMM1

    // 1. CSR build + dinv + weight split + x->bf16
    hipMemsetAsync(deg_i, 0, 2 * 200704, stream);
    k_deg_count<<<(N_EDGES + 255) / 256, 256, 0, stream>>>(dst, deg_i);
    k_scan_blk<<<SCAN_NBLK, SCAN_BLK, 0, stream>>>(deg_i, row_start, dinv, blk_tot);
    k_scan_add<<<SCAN_NBLK, SCAN_BLK, 0, stream>>>(row_start, blk_tot);
    k_csr_fill<<<(N_EDGES + 255) / 256, 256, 0, stream>>>(src, dst, row_start, cursor, col);
    k_x2bf<<<(N_NODES * IN_DIM / 4 + 255) / 256, 256, 0, stream>>>(x, xb);
    k_wsplit<<<(IN_DIM * 256 + 255) / 256, 256, 0, stream>>>(W1, Bh1, Bl1, IN_DIM);
    k_wsplit<<<(HID_DIM * 256 + 255) / 256, 256, 0, stream>>>(W2, Bh2, Bl2, HID_DIM);
    k_bounds_init<<<1, 512, 0, stream>>>(batch, bounds, sums);

    const int gemm_grid = (N_NODES + 63) / 64;  // 782

    // 2. layer 1: (zh,zl) = split(A_hat @ x) ; (h1h,h1l) = split(relu(z @ W1 + b1))
    k_agg_x<<<N_NODES / 4, 256, 0, stream>>>(x, xb, row_start, col, dinv, zh, zl);
    k_gemm_mfma<1><<<gemm_grid, 256, 0, stream>>>(zh, zl, Bh1, Bl1, dinv, b1, h1h, h1l, nullptr, N_NODES, IN_DIM);

    // 3. layer 2: y2b = bf16((h1 @ W2) * dinv) ; fused agg+relu+pool
    k_gemm_mfma<0><<<gemm_grid, 256, 0, stream>>>(h1h, h1l, Bh2, Bl2, dinv, b2, nullptr, nullptr, y2b, N_NODES, HID_DIM);
    k_agg_pool<<<N_NODES / 8, 512, 0, stream>>>(y2b, row_start, col, dinv, b2, batch, sums);

    // 4. fc
    k_final<<<N_GRAPHS, HID_DIM, 0, stream>>>(sums, bounds, Wfc, bfc, out);
}

// Round 12
// 260.120 us; speedup vs baseline: 1.6105x; 1.0803x over previous
//
#include <hip/hip_runtime.h>
#include <hip/hip_bf16.h>

#define N_NODES 50000
#define N_EDGES 800000
#define N_GRAPHS 64
#define IN_DIM 128
#define HID_DIM 256
#define M_PAD 50048   // N_NODES padded to multiple of 64 for GEMM staging

typedef short sh8 __attribute__((ext_vector_type(8)));
typedef float f4 __attribute__((ext_vector_type(4)));
typedef unsigned short us4 __attribute__((ext_vector_type(4)));
typedef unsigned short us8 __attribute__((ext_vector_type(8)));

__device__ __forceinline__ unsigned short bf16rne(float f) {
    unsigned int u = __float_as_uint(f);
    return (unsigned short)((u + 0x7FFFu + ((u >> 16) & 1u)) >> 16);
}
__device__ __forceinline__ float bf2f(unsigned short b) {
    return __uint_as_float((unsigned int)b << 16);
}
__device__ __forceinline__ void split_bf16(float f, unsigned short& h, unsigned short& l) {
    unsigned int u = __float_as_uint(f);
    unsigned int hb = (u + 0x7FFFu + ((u >> 16) & 1u)) & 0xFFFF0000u;  // RNE
    h = (unsigned short)(hb >> 16);
    float rest = f - __uint_as_float(hb);
    unsigned int u2 = __float_as_uint(rest);
    l = (unsigned short)((u2 + 0x7FFFu + ((u2 >> 16) & 1u)) >> 16);
}

// async 16B global -> LDS (direct, no VGPR round-trip)
__device__ __forceinline__ void gl2lds16(const unsigned short* g, unsigned short* l) {
    __builtin_amdgcn_global_load_lds(
        (const __attribute__((address_space(1))) void*)g,
        (__attribute__((address_space(3))) void*)l, 16, 0, 0);
}

// ---------------- degree / CSR build ----------------

__global__ void k_deg_count(const int* __restrict__ dst, int* __restrict__ deg) {
    int e = blockIdx.x * blockDim.x + threadIdx.x;
    if (e < N_EDGES) atomicAdd(&deg[dst[e]], 1);
}

#define SCAN_BLK 1024
#define SCAN_NBLK ((N_NODES + SCAN_BLK - 1) / SCAN_BLK)  // 49

__global__ __launch_bounds__(SCAN_BLK)
void k_scan_blk(const int* __restrict__ deg, int* __restrict__ row_start,
                float* __restrict__ dinv, int* __restrict__ blk_tot) {
    __shared__ int tmp[SCAN_BLK];
    int t = threadIdx.x;
    int i = blockIdx.x * SCAN_BLK + t;
    int d = 0;
    if (i < N_NODES) {
        d = deg[i];
        dinv[i] = rsqrtf((float)d + 1.0f);
    }
    tmp[t] = d;
    __syncthreads();
    #pragma unroll
    for (int off = 1; off < SCAN_BLK; off <<= 1) {
        int v = (t >= off) ? tmp[t - off] : 0;
        __syncthreads();
        tmp[t] += v;
        __syncthreads();
    }
    if (i < N_NODES) row_start[i] = tmp[t] - d;
    if (t == SCAN_BLK - 1) blk_tot[blockIdx.x] = tmp[t];
}

__global__ __launch_bounds__(SCAN_BLK)
void k_scan_add(int* __restrict__ row_start, const int* __restrict__ blk_tot) {
    __shared__ int soff;
    int t = threadIdx.x;
    int bid = blockIdx.x;
    if (t < 64) {
        int v = (t < bid) ? blk_tot[t] : 0;
        #pragma unroll
        for (int m = 1; m < 64; m <<= 1) v += __shfl_xor(v, m, 64);
        if (t == 0) soff = v;
    }
    __syncthreads();
    int i = bid * SCAN_BLK + t;
    if (i < N_NODES) row_start[i] += soff;
    if (bid == 0 && t == 0) row_start[N_NODES] = N_EDGES;
}

__global__ void k_csr_fill(const int* __restrict__ src, const int* __restrict__ dst,
                           const int* __restrict__ row_start, int* __restrict__ cursor,
                           int* __restrict__ col) {
    int e = blockIdx.x * blockDim.x + threadIdx.x;
    if (e < N_EDGES) {
        int d = dst[e];
        int pos = atomicAdd(&cursor[d], 1);
        col[row_start[d] + pos] = src[e];
    }
}

// ---------------- merged prologue: x->bf16, W splits, bounds, sums zero ----

__device__ __forceinline__ void wsplit_one(const float* __restrict__ W,
                                           unsigned short* __restrict__ Bh,
                                           unsigned short* __restrict__ Bl, int i) {
    int k = i >> 8, c = i & 255;
    unsigned short h, l;
    split_bf16(W[i], h, l);
    size_t pos = (size_t)(k >> 5) * 8192 + (size_t)(((c >> 4) * 4 + ((k >> 3) & 3)) * 128 + (c & 15) * 8 + (k & 7));
    Bh[pos] = h;
    Bl[pos] = l;
}

__global__ __launch_bounds__(256)
void k_prep(const float* __restrict__ x, unsigned short* __restrict__ xb,
            const float* __restrict__ W1, unsigned short* __restrict__ Bh1, unsigned short* __restrict__ Bl1,
            const float* __restrict__ W2, unsigned short* __restrict__ Bh2, unsigned short* __restrict__ Bl2,
            const int* __restrict__ batch, int* __restrict__ bounds, float* __restrict__ sums) {
    const int T = gridDim.x * 256;
    const int gid = blockIdx.x * 256 + threadIdx.x;
    // x -> bf16 (us4 granules)
    for (int i = gid; i < N_NODES * IN_DIM / 4; i += T) {
        float4 v = ((const float4*)x)[i];
        us4 o;
        o.x = bf16rne(v.x); o.y = bf16rne(v.y); o.z = bf16rne(v.z); o.w = bf16rne(v.w);
        ((us4*)xb)[i] = o;
    }
    for (int i = gid; i < IN_DIM * 256; i += T) wsplit_one(W1, Bh1, Bl1, i);
    for (int i = gid; i < HID_DIM * 256; i += T) wsplit_one(W2, Bh2, Bl2, i);
    for (int i = gid; i < N_GRAPHS * HID_DIM; i += T) sums[i] = 0.f;
    if (gid <= N_GRAPHS) {
        int lo = 0, hi = N_NODES;
        while (lo < hi) {
            int mid = (lo + hi) >> 1;
            if (batch[mid] < gid) lo = mid + 1; else hi = mid;
        }
        bounds[gid] = lo;
    }
}

// ---------------- MFMA GEMM: [M,256] = epilogue(A[M,K] @ B[K,256]) --------
// B pre-split hi/lo, fragment-major. 64x256 tile, 4 waves, K-step 32.
// MODE 1 (layer 1): A = (Ah,Al) 3-pass hi/lo; Cout = bf16(relu(acc + bias[c]))
// MODE 0 (layer 2): A = Ah only, 2-pass (Ah*Bh + Ah*Bl); Cout = bf16(acc * dinv[m])

template<int MODE>
__global__ __launch_bounds__(256)
void k_gemm_mfma(const unsigned short* __restrict__ Ah, const unsigned short* __restrict__ Al,
                 const unsigned short* __restrict__ Bh, const unsigned short* __restrict__ Bl,
                 const float* __restrict__ dinv, const float* __restrict__ bias,
                 unsigned short* __restrict__ Cout, int M, int K) {
    __shared__ unsigned short AhL[2048], AlL[2048];
    __shared__ unsigned short BhL[8192], BlL[8192];

    const int tid = threadIdx.x;
    const int wv = tid >> 6, lane = tid & 63;
    const int m0 = blockIdx.x * 64;

    const int ar = wv * 16 + (lane & 15);
    const int kseg = lane >> 4;
    const unsigned short* aph = Ah + (size_t)(m0 + ar) * K + kseg * 8;
    const unsigned short* apl = (MODE == 1) ? Al + (size_t)(m0 + ar) * K + kseg * 8 : nullptr;
    unsigned short* adh = &AhL[(wv * 64 + lane) * 8];
    unsigned short* adl = &AlL[(wv * 64 + lane) * 8];

    f4 acc[4][4];
    #pragma unroll
    for (int mi = 0; mi < 4; ++mi)
        #pragma unroll
        for (int nj = 0; nj < 4; ++nj)
            acc[mi][nj] = f4{0.f, 0.f, 0.f, 0.f};

    const int nsteps = K >> 5;
    for (int s = 0; s < nsteps; ++s) {
        __syncthreads();  // prior iteration's LDS reads complete
        gl2lds16(aph + s * 32, adh);
        if (MODE == 1) gl2lds16(apl + s * 32, adl);
        {
            const unsigned short* gb = Bh + (size_t)s * 8192;
            const unsigned short* gl = Bl + (size_t)s * 8192;
            #pragma unroll
            for (int j = 0; j < 4; ++j) {
                gl2lds16(gb + j * 2048 + tid * 8, &BhL[j * 2048 + tid * 8]);
                gl2lds16(gl + j * 2048 + tid * 8, &BlL[j * 2048 + tid * 8]);
            }
        }
        __syncthreads();  // drains vmcnt -> staged data visible

        sh8 afh[4], afl[4], bfh[4], bfl[4];
        #pragma unroll
        for (int mi = 0; mi < 4; ++mi) {
            afh[mi] = *reinterpret_cast<const sh8*>(&AhL[mi * 512 + lane * 8]);
            if (MODE == 1)
                afl[mi] = *reinterpret_cast<const sh8*>(&AlL[mi * 512 + lane * 8]);
        }
        #pragma unroll
        for (int nj = 0; nj < 4; ++nj) {
            bfh[nj] = *reinterpret_cast<const sh8*>(&BhL[(wv * 4 + nj) * 512 + lane * 8]);
            bfl[nj] = *reinterpret_cast<const sh8*>(&BlL[(wv * 4 + nj) * 512 + lane * 8]);
        }
        #pragma unroll
        for (int mi = 0; mi < 4; ++mi) {
            #pragma unroll
            for (int nj = 0; nj < 4; ++nj) {
                acc[mi][nj] = __builtin_amdgcn_mfma_f32_16x16x32_bf16(afh[mi], bfh[nj], acc[mi][nj], 0, 0, 0);
                acc[mi][nj] = __builtin_amdgcn_mfma_f32_16x16x32_bf16(afh[mi], bfl[nj], acc[mi][nj], 0, 0, 0);
                if (MODE == 1)
                    acc[mi][nj] = __builtin_amdgcn_mfma_f32_16x16x32_bf16(afl[mi], bfh[nj], acc[mi][nj], 0, 0, 0);
            }
        }
    }

    #pragma unroll
    for (int mi = 0; mi < 4; ++mi) {
        #pragma unroll
        for (int q = 0; q < 4; ++q) {
            int grow = m0 + mi * 16 + (lane >> 4) * 4 + q;
            if (grow < M) {
                float dm = (MODE == 0) ? dinv[grow] : 0.f;
                #pragma unroll
                for (int nj = 0; nj < 4; ++nj) {
                    int gcol = wv * 64 + nj * 16 + (lane & 15);
                    float v = acc[mi][nj][q];
                    if (MODE == 0) {
                        Cout[(size_t)grow * 256 + gcol] = bf16rne(v * dm);
                    } else {
                        Cout[(size_t)grow * 256 + gcol] = bf16rne(fmaxf(v + bias[gcol], 0.f));
                    }
                }
            }
        }
    }
}

// ---------------- aggregation (round-9 proven shapes) ----------------

// layer-1: z[n] = dinv[n] * ( dinv[n]*x[n] + sum dinv[s]*xb[s] )
// Half-wave dual-edge + 4x unroll. Outputs hi/lo planes.
__global__ __launch_bounds__(256)
void k_agg_x(const float* __restrict__ x, const unsigned short* __restrict__ xb,
             const int* __restrict__ row_start, const int* __restrict__ col,
             const float* __restrict__ dinv,
             unsigned short* __restrict__ zh, unsigned short* __restrict__ zl) {
    int wv = threadIdx.x >> 6, lane = threadIdx.x & 63;
    int half = lane >> 5, sub = lane & 31;
    int n = blockIdx.x * 4 + wv;

    float a0 = 0.f, a1 = 0.f, a2 = 0.f, a3 = 0.f;
    float dn = dinv[n];
    if (half == 0) {
        float4 xs = ((const float4*)x)[(size_t)n * 32 + sub];
        a0 = xs.x * dn; a1 = xs.y * dn; a2 = xs.z * dn; a3 = xs.w * dn;
    }
    const us4* xb4 = (const us4*)xb;
    int e = row_start[n] + half;
    const int e1 = row_start[n + 1];
    for (; e + 6 < e1; e += 8) {
        int s0 = col[e], s1 = col[e + 2], s2 = col[e + 4], s3 = col[e + 6];
        float d0 = dinv[s0], d1 = dinv[s1], d2 = dinv[s2], d3 = dinv[s3];
        us4 v0 = xb4[(size_t)s0 * 32 + sub];
        us4 v1 = xb4[(size_t)s1 * 32 + sub];
        us4 v2 = xb4[(size_t)s2 * 32 + sub];
        us4 v3 = xb4[(size_t)s3 * 32 + sub];
        a0 += bf2f(v0.x) * d0 + bf2f(v1.x) * d1 + bf2f(v2.x) * d2 + bf2f(v3.x) * d3;
        a1 += bf2f(v0.y) * d0 + bf2f(v1.y) * d1 + bf2f(v2.y) * d2 + bf2f(v3.y) * d3;
        a2 += bf2f(v0.z) * d0 + bf2f(v1.z) * d1 + bf2f(v2.z) * d2 + bf2f(v3.z) * d3;
        a3 += bf2f(v0.w) * d0 + bf2f(v1.w) * d1 + bf2f(v2.w) * d2 + bf2f(v3.w) * d3;
    }
    for (; e < e1; e += 2) {
        int s = col[e];
        float ds = dinv[s];
        us4 v = xb4[(size_t)s * 32 + sub];
        a0 += bf2f(v.x) * ds; a1 += bf2f(v.y) * ds;
        a2 += bf2f(v.z) * ds; a3 += bf2f(v.w) * ds;
    }
    a0 += __shfl_xor(a0, 32, 64);
    a1 += __shfl_xor(a1, 32, 64);
    a2 += __shfl_xor(a2, 32, 64);
    a3 += __shfl_xor(a3, 32, 64);
    if (half == 0) {
        float o[4] = {a0 * dn, a1 * dn, a2 * dn, a3 * dn};
        us4 oh, ol;
        #pragma unroll
        for (int j = 0; j < 4; ++j) {
            unsigned short h, l;
            split_bf16(o[j], h, l);
            oh[j] = h; ol[j] = l;
        }
        ((us4*)zh)[(size_t)n * 32 + sub] = oh;
        ((us4*)zl)[(size_t)n * 32 + sub] = ol;
    }
}

// layer-2 agg + relu + mean-pool fused. yb pre-scaled by dinv[src] (bf16).
// 8 nodes per 512-thread block. Half-wave dual-edge + 4x unroll.
__global__ __launch_bounds__(512)
void k_agg_pool(const unsigned short* __restrict__ yb, const int* __restrict__ row_start,
                const int* __restrict__ col, const float* __restrict__ dinv,
                const float* __restrict__ bias, const int* __restrict__ batch,
                float* __restrict__ sums) {
    __shared__ float lsum[8][256];
    const int tid = threadIdx.x;
    const int wv = tid >> 6, lane = tid & 63;
    const int half = lane >> 5, sub = lane & 31;
    const int base = blockIdx.x * 8;
    const int n = base + wv;

    const bool uni = (batch[base] == batch[base + 7]);

    const us8* y8 = (const us8*)yb;
    float a[8] = {0.f, 0.f, 0.f, 0.f, 0.f, 0.f, 0.f, 0.f};
    if (half == 0) {
        us8 sv = y8[(size_t)n * 32 + sub];
        #pragma unroll
        for (int j = 0; j < 8; ++j) a[j] = bf2f(sv[j]);
    }
    int e = row_start[n] + half;
    const int e1 = row_start[n + 1];
    for (; e + 6 < e1; e += 8) {
        int s0 = col[e], s1 = col[e + 2], s2 = col[e + 4], s3 = col[e + 6];
        us8 v0 = y8[(size_t)s0 * 32 + sub];
        us8 v1 = y8[(size_t)s1 * 32 + sub];
        us8 v2 = y8[(size_t)s2 * 32 + sub];
        us8 v3 = y8[(size_t)s3 * 32 + sub];
        #pragma unroll
        for (int j = 0; j < 8; ++j)
            a[j] += (bf2f(v0[j]) + bf2f(v1[j])) + (bf2f(v2[j]) + bf2f(v3[j]));
    }
    for (; e < e1; e += 2) {
        int s = col[e];
        us8 v = y8[(size_t)s * 32 + sub];
        #pragma unroll
        for (int j = 0; j < 8; ++j) a[j] += bf2f(v[j]);
    }
    #pragma unroll
    for (int j = 0; j < 8; ++j) a[j] += __shfl_xor(a[j], 32, 64);

    if (half == 0) {
        float dn = dinv[n];
        float4 b0 = ((const float4*)bias)[sub * 2];
        float4 b1 = ((const float4*)bias)[sub * 2 + 1];
        float4 o0, o1;
        o0.x = fmaxf(a[0] * dn + b0.x, 0.f);
        o0.y = fmaxf(a[1] * dn + b0.y, 0.f);
        o0.z = fmaxf(a[2] * dn + b0.z, 0.f);
        o0.w = fmaxf(a[3] * dn + b0.w, 0.f);
        o1.x = fmaxf(a[4] * dn + b1.x, 0.f);
        o1.y = fmaxf(a[5] * dn + b1.y, 0.f);
        o1.z = fmaxf(a[6] * dn + b1.z, 0.f);
        o1.w = fmaxf(a[7] * dn + b1.w, 0.f);
        if (uni) {
            ((float4*)&lsum[wv][sub * 8])[0] = o0;
            ((float4*)&lsum[wv][sub * 8])[1] = o1;
        } else {
            int g = batch[n];
            atomicAdd(&sums[g * 256 + sub * 8 + 0], o0.x);
            atomicAdd(&sums[g * 256 + sub * 8 + 1], o0.y);
            atomicAdd(&sums[g * 256 + sub * 8 + 2], o0.z);
            atomicAdd(&sums[g * 256 + sub * 8 + 3], o0.w);
            atomicAdd(&sums[g * 256 + sub * 8 + 4], o1.x);
            atomicAdd(&sums[g * 256 + sub * 8 + 5], o1.y);
            atomicAdd(&sums[g * 256 + sub * 8 + 6], o1.z);
            atomicAdd(&sums[g * 256 + sub * 8 + 7], o1.w);
        }
    }
    __syncthreads();
    if (uni && tid < 256) {
        float v = 0.f;
        #pragma unroll
        for (int w = 0; w < 8; ++w) v += lsum[w][tid];
        atomicAdd(&sums[batch[base] * 256 + tid], v);
    }
}

// ---------------- FC ----------------

__global__ void k_final(const float* __restrict__ sums, const int* __restrict__ bounds,
                        const float* __restrict__ Wfc, const float* __restrict__ bfc,
                        float* __restrict__ out) {
    __shared__ float red[HID_DIM];
    int g = blockIdx.x;
    int c = threadIdx.x;
    float cnt = (float)(bounds[g + 1] - bounds[g]);
    float v = sums[g * HID_DIM + c] / fmaxf(cnt, 1.0f) * Wfc[c];
    red[c] = v;
    __syncthreads();
    for (int s = HID_DIM / 2; s > 0; s >>= 1) {
        if (c < s) red[c] += red[c + s];
        __syncthreads();
    }
    if (c == 0) out[g] = red[0] + bfc[0];
}

// ---------------- launch ----------------

extern "C" void kernel_launch(void* const* d_in, const int* in_sizes, int n_in,
                              void* d_out, int out_size, void* d_ws, size_t ws_size,
                              hipStream_t stream) {
    const float* x    = (const float*)d_in[0];
    const int*   ei   = (const int*)d_in[1];
    const int*   batch= (const int*)d_in[2];
    const float* W1   = (const float*)d_in[3];
    const float* b1   = (const float*)d_in[4];
    const float* W2   = (const float*)d_in[5];
    const float* b2   = (const float*)d_in[6];
    const float* Wfc  = (const float*)d_in[7];
    const float* bfc  = (const float*)d_in[8];
    float* out = (float*)d_out;

    const int* src = ei;
    const int* dst = ei + N_EDGES;

    char* ws = (char*)d_ws;
    const size_t PLANE256 = (size_t)M_PAD * 256 * 2;
    const size_t PLANE128 = (size_t)M_PAD * 128 * 2;
    size_t off = 0;
    unsigned short* h1h = (unsigned short*)(ws + off); off += PLANE256;
    unsigned short* zh  = (unsigned short*)(ws + off); off += PLANE128;  // y2b overlays zh+zl
    unsigned short* zl  = (unsigned short*)(ws + off); off += PLANE128;
    unsigned short* xb  = (unsigned short*)(ws + off); off += (size_t)N_NODES * 128 * 2;
    int*   deg_i     = (int*)  (ws + off); off += 200704;
    int*   cursor    = (int*)  (ws + off); off += 200704;
    float* dinv      = (float*)(ws + off); off += 200704;
    int*   row_start = (int*)  (ws + off); off += 200704;
    int*   col       = (int*)  (ws + off); off += (size_t)N_EDGES * 4;
    unsigned short* Bh1 = (unsigned short*)(ws + off); off += 65536;
    unsigned short* Bl1 = (unsigned short*)(ws + off); off += 65536;
    unsigned short* Bh2 = (unsigned short*)(ws + off); off += 131072;
    unsigned short* Bl2 = (unsigned short*)(ws + off); off += 131072;
    float* sums      = (float*)(ws + off); off += 65536;
    int*   bounds    = (int*)  (ws + off); off += 512;
    int*   blk_tot   = (int*)  (ws + off); off += 512;
    (void)ws_size; (void)in_sizes; (void)n_in; (void)out_size;

    unsigned short* y2b = zh;  // z planes dead after GEMM1

    // 1. CSR build + dinv + merged prologue
    hipMemsetAsync(deg_i, 0, 2 * 200704, stream);
    k_deg_count<<<(N_EDGES + 255) / 256, 256, 0, stream>>>(dst, deg_i);
    k_scan_blk<<<SCAN_NBLK, SCAN_BLK, 0, stream>>>(deg_i, row_start, dinv, blk_tot);
    k_scan_add<<<SCAN_NBLK, SCAN_BLK, 0, stream>>>(row_start, blk_tot);
    k_csr_fill<<<(N_EDGES + 255) / 256, 256, 0, stream>>>(src, dst, row_start, cursor, col);
    k_prep<<<2048, 256, 0, stream>>>(x, xb, W1, Bh1, Bl1, W2, Bh2, Bl2, batch, bounds, sums);

    const int gemm_grid = (N_NODES + 63) / 64;  // 782

    // 2. layer 1: (zh,zl) = split(A_hat @ x) ; h1h = bf16(relu(z @ W1 + b1))
    k_agg_x<<<N_NODES / 4, 256, 0, stream>>>(x, xb, row_start, col, dinv, zh, zl);
    k_gemm_mfma<1><<<gemm_grid, 256, 0, stream>>>(zh, zl, Bh1, Bl1, dinv, b1, h1h, N_NODES, IN_DIM);

    // 3. layer 2 (2-pass A): y2b = bf16((h1 @ W2) * dinv) ; fused agg+relu+pool
    k_gemm_mfma<0><<<gemm_grid, 256, 0, stream>>>(h1h, nullptr, Bh2, Bl2, dinv, b2, y2b, N_NODES, HID_DIM);
    k_agg_pool<<<N_NODES / 8, 512, 0, stream>>>(y2b, row_start, col, dinv, b2, batch, sums);

    // 4. fc
    k_final<<<N_GRAPHS, HID_DIM, 0, stream>>>(sums, bounds, Wfc, bfc, out);
}

// Round 13
// 259.184 us; speedup vs baseline: 1.6163x; 1.0036x over previous
//
#include <hip/hip_runtime.h>
#include <hip/hip_bf16.h>

#define N_NODES 50000
#define N_EDGES 800000
#define N_GRAPHS 64
#define IN_DIM 128
#define HID_DIM 256
#define M_PAD 50048   // N_NODES padded to multiple of 64 for GEMM staging

typedef short sh8 __attribute__((ext_vector_type(8)));
typedef float f4 __attribute__((ext_vector_type(4)));
typedef unsigned short us4 __attribute__((ext_vector_type(4)));
typedef unsigned short us8 __attribute__((ext_vector_type(8)));

__device__ __forceinline__ unsigned short bf16rne(float f) {
    unsigned int u = __float_as_uint(f);
    return (unsigned short)((u + 0x7FFFu + ((u >> 16) & 1u)) >> 16);
}
__device__ __forceinline__ float bf2f(unsigned short b) {
    return __uint_as_float((unsigned int)b << 16);
}
__device__ __forceinline__ void split_bf16(float f, unsigned short& h, unsigned short& l) {
    unsigned int u = __float_as_uint(f);
    unsigned int hb = (u + 0x7FFFu + ((u >> 16) & 1u)) & 0xFFFF0000u;  // RNE
    h = (unsigned short)(hb >> 16);
    float rest = f - __uint_as_float(hb);
    unsigned int u2 = __float_as_uint(rest);
    l = (unsigned short)((u2 + 0x7FFFu + ((u2 >> 16) & 1u)) >> 16);
}

// async 16B global -> LDS (direct, no VGPR round-trip)
__device__ __forceinline__ void gl2lds16(const unsigned short* g, unsigned short* l) {
    __builtin_amdgcn_global_load_lds(
        (const __attribute__((address_space(1))) void*)g,
        (__attribute__((address_space(3))) void*)l, 16, 0, 0);
}

// ---------------- degree / CSR build ----------------

__global__ void k_deg_count(const int* __restrict__ dst, int* __restrict__ deg) {
    int e = blockIdx.x * blockDim.x + threadIdx.x;
    if (e < N_EDGES) atomicAdd(&deg[dst[e]], 1);
}

#define SCAN_BLK 1024
#define SCAN_NBLK ((N_NODES + SCAN_BLK - 1) / SCAN_BLK)  // 49

__global__ __launch_bounds__(SCAN_BLK)
void k_scan_blk(const int* __restrict__ deg, int* __restrict__ row_start,
                float* __restrict__ dinv, int* __restrict__ blk_tot) {
    __shared__ int tmp[SCAN_BLK];
    int t = threadIdx.x;
    int i = blockIdx.x * SCAN_BLK + t;
    int d = 0;
    if (i < N_NODES) {
        d = deg[i];
        dinv[i] = rsqrtf((float)d + 1.0f);
    }
    tmp[t] = d;
    __syncthreads();
    #pragma unroll
    for (int off = 1; off < SCAN_BLK; off <<= 1) {
        int v = (t >= off) ? tmp[t - off] : 0;
        __syncthreads();
        tmp[t] += v;
        __syncthreads();
    }
    if (i < N_NODES) row_start[i] = tmp[t] - d;
    if (t == SCAN_BLK - 1) blk_tot[blockIdx.x] = tmp[t];
}

__global__ __launch_bounds__(SCAN_BLK)
void k_scan_add(int* __restrict__ row_start, const int* __restrict__ blk_tot) {
    __shared__ int soff;
    int t = threadIdx.x;
    int bid = blockIdx.x;
    if (t < 64) {
        int v = (t < bid) ? blk_tot[t] : 0;
        #pragma unroll
        for (int m = 1; m < 64; m <<= 1) v += __shfl_xor(v, m, 64);
        if (t == 0) soff = v;
    }
    __syncthreads();
    int i = bid * SCAN_BLK + t;
    if (i < N_NODES) row_start[i] += soff;
    if (bid == 0 && t == 0) row_start[N_NODES] = N_EDGES;
}

__global__ void k_csr_fill(const int* __restrict__ src, const int* __restrict__ dst,
                           const int* __restrict__ row_start, int* __restrict__ cursor,
                           int* __restrict__ col) {
    int e = blockIdx.x * blockDim.x + threadIdx.x;
    if (e < N_EDGES) {
        int d = dst[e];
        int pos = atomicAdd(&cursor[d], 1);
        col[row_start[d] + pos] = src[e];
    }
}

// ---------------- merged prologue: x->bf16, W splits, bounds, sums zero ----

__device__ __forceinline__ void wsplit_one(const float* __restrict__ W,
                                           unsigned short* __restrict__ Bh,
                                           unsigned short* __restrict__ Bl, int i) {
    int k = i >> 8, c = i & 255;
    unsigned short h, l;
    split_bf16(W[i], h, l);
    size_t pos = (size_t)(k >> 5) * 8192 + (size_t)(((c >> 4) * 4 + ((k >> 3) & 3)) * 128 + (c & 15) * 8 + (k & 7));
    Bh[pos] = h;
    Bl[pos] = l;
}

__global__ __launch_bounds__(256)
void k_prep(const float* __restrict__ x, unsigned short* __restrict__ xb,
            const float* __restrict__ W1, unsigned short* __restrict__ Bh1, unsigned short* __restrict__ Bl1,
            const float* __restrict__ W2, unsigned short* __restrict__ Bh2, unsigned short* __restrict__ Bl2,
            const int* __restrict__ batch, int* __restrict__ bounds, float* __restrict__ sums) {
    const int T = gridDim.x * 256;
    const int gid = blockIdx.x * 256 + threadIdx.x;
    for (int i = gid; i < N_NODES * IN_DIM / 4; i += T) {
        float4 v = ((const float4*)x)[i];
        us4 o;
        o.x = bf16rne(v.x); o.y = bf16rne(v.y); o.z = bf16rne(v.z); o.w = bf16rne(v.w);
        ((us4*)xb)[i] = o;
    }
    for (int i = gid; i < IN_DIM * 256; i += T) wsplit_one(W1, Bh1, Bl1, i);
    for (int i = gid; i < HID_DIM * 256; i += T) wsplit_one(W2, Bh2, Bl2, i);
    for (int i = gid; i < N_GRAPHS * HID_DIM; i += T) sums[i] = 0.f;
    if (gid <= N_GRAPHS) {
        int lo = 0, hi = N_NODES;
        while (lo < hi) {
            int mid = (lo + hi) >> 1;
            if (batch[mid] < gid) lo = mid + 1; else hi = mid;
        }
        bounds[gid] = lo;
    }
}

// ---------------- MFMA GEMM: [M,256] = epilogue(A[M,K] @ B[K,256]) --------
// A: bf16 plane, staged via global_load_lds into double-buffered LDS (1 barrier/step).
// B: hi/lo fragment-major global images, read DIRECTLY to registers (L2-resident,
//    1KB coalesced per wave per plane per step). 2-pass: A*Bh + A*Bl.
// MODE 0: Cout = bf16(acc * dinv[m]);  MODE 1: Cout = bf16(relu(acc + bias[c]))

template<int MODE>
__global__ __launch_bounds__(256)
void k_gemm_mfma(const unsigned short* __restrict__ Ah,
                 const unsigned short* __restrict__ Bh, const unsigned short* __restrict__ Bl,
                 const float* __restrict__ dinv, const float* __restrict__ bias,
                 unsigned short* __restrict__ Cout, int M, int K) {
    __shared__ unsigned short AhL[2][2048];

    const int tid = threadIdx.x;
    const int wv = tid >> 6, lane = tid & 63;
    const int m0 = blockIdx.x * 64;

    const int ar = wv * 16 + (lane & 15);
    const int kseg = lane >> 4;
    const unsigned short* aph = Ah + (size_t)(m0 + ar) * K + kseg * 8;
    const int adoff = (wv * 64 + lane) * 8;

    f4 acc[4][4];
    #pragma unroll
    for (int mi = 0; mi < 4; ++mi)
        #pragma unroll
        for (int nj = 0; nj < 4; ++nj)
            acc[mi][nj] = f4{0.f, 0.f, 0.f, 0.f};

    const int nsteps = K >> 5;
    gl2lds16(aph, &AhL[0][adoff]);  // prologue: stage A(0)

    for (int s = 0; s < nsteps; ++s) {
        __syncthreads();  // drains vmcnt -> A(s) visible to all waves
        const int cur = s & 1;

        // B fragments direct from global (each wave: 1KB contiguous per plane)
        const unsigned short* gb = Bh + (size_t)s * 8192 + wv * 2048 + lane * 8;
        const unsigned short* gl = Bl + (size_t)s * 8192 + wv * 2048 + lane * 8;
        sh8 bfh[4], bfl[4];
        #pragma unroll
        for (int nj = 0; nj < 4; ++nj) {
            bfh[nj] = *reinterpret_cast<const sh8*>(gb + nj * 512);
            bfl[nj] = *reinterpret_cast<const sh8*>(gl + nj * 512);
        }

        sh8 afh[4];
        #pragma unroll
        for (int mi = 0; mi < 4; ++mi)
            afh[mi] = *reinterpret_cast<const sh8*>(&AhL[cur][mi * 512 + lane * 8]);

        if (s + 1 < nsteps) gl2lds16(aph + (s + 1) * 32, &AhL[cur ^ 1][adoff]);

        #pragma unroll
        for (int mi = 0; mi < 4; ++mi) {
            #pragma unroll
            for (int nj = 0; nj < 4; ++nj) {
                acc[mi][nj] = __builtin_amdgcn_mfma_f32_16x16x32_bf16(afh[mi], bfh[nj], acc[mi][nj], 0, 0, 0);
                acc[mi][nj] = __builtin_amdgcn_mfma_f32_16x16x32_bf16(afh[mi], bfl[nj], acc[mi][nj], 0, 0, 0);
            }
        }
    }

    #pragma unroll
    for (int mi = 0; mi < 4; ++mi) {
        #pragma unroll
        for (int q = 0; q < 4; ++q) {
            int grow = m0 + mi * 16 + (lane >> 4) * 4 + q;
            if (grow < M) {
                float dm = (MODE == 0) ? dinv[grow] : 0.f;
                #pragma unroll
                for (int nj = 0; nj < 4; ++nj) {
                    int gcol = wv * 64 + nj * 16 + (lane & 15);
                    float v = acc[mi][nj][q];
                    if (MODE == 0) {
                        Cout[(size_t)grow * 256 + gcol] = bf16rne(v * dm);
                    } else {
                        Cout[(size_t)grow * 256 + gcol] = bf16rne(fmaxf(v + bias[gcol], 0.f));
                    }
                }
            }
        }
    }
}

// ---------------- aggregation (round-9 proven shapes) ----------------

// layer-1: z[n] = dinv[n] * ( dinv[n]*x[n] + sum dinv[s]*xb[s] )
// Half-wave dual-edge + 4x unroll. Output: bf16 plane zh (single).
__global__ __launch_bounds__(256)
void k_agg_x(const float* __restrict__ x, const unsigned short* __restrict__ xb,
             const int* __restrict__ row_start, const int* __restrict__ col,
             const float* __restrict__ dinv, unsigned short* __restrict__ zh) {
    int wv = threadIdx.x >> 6, lane = threadIdx.x & 63;
    int half = lane >> 5, sub = lane & 31;
    int n = blockIdx.x * 4 + wv;

    float a0 = 0.f, a1 = 0.f, a2 = 0.f, a3 = 0.f;
    float dn = dinv[n];
    if (half == 0) {
        float4 xs = ((const float4*)x)[(size_t)n * 32 + sub];
        a0 = xs.x * dn; a1 = xs.y * dn; a2 = xs.z * dn; a3 = xs.w * dn;
    }
    const us4* xb4 = (const us4*)xb;
    int e = row_start[n] + half;
    const int e1 = row_start[n + 1];
    for (; e + 6 < e1; e += 8) {
        int s0 = col[e], s1 = col[e + 2], s2 = col[e + 4], s3 = col[e + 6];
        float d0 = dinv[s0], d1 = dinv[s1], d2 = dinv[s2], d3 = dinv[s3];
        us4 v0 = xb4[(size_t)s0 * 32 + sub];
        us4 v1 = xb4[(size_t)s1 * 32 + sub];
        us4 v2 = xb4[(size_t)s2 * 32 + sub];
        us4 v3 = xb4[(size_t)s3 * 32 + sub];
        a0 += bf2f(v0.x) * d0 + bf2f(v1.x) * d1 + bf2f(v2.x) * d2 + bf2f(v3.x) * d3;
        a1 += bf2f(v0.y) * d0 + bf2f(v1.y) * d1 + bf2f(v2.y) * d2 + bf2f(v3.y) * d3;
        a2 += bf2f(v0.z) * d0 + bf2f(v1.z) * d1 + bf2f(v2.z) * d2 + bf2f(v3.z) * d3;
        a3 += bf2f(v0.w) * d0 + bf2f(v1.w) * d1 + bf2f(v2.w) * d2 + bf2f(v3.w) * d3;
    }
    for (; e < e1; e += 2) {
        int s = col[e];
        float ds = dinv[s];
        us4 v = xb4[(size_t)s * 32 + sub];
        a0 += bf2f(v.x) * ds; a1 += bf2f(v.y) * ds;
        a2 += bf2f(v.z) * ds; a3 += bf2f(v.w) * ds;
    }
    a0 += __shfl_xor(a0, 32, 64);
    a1 += __shfl_xor(a1, 32, 64);
    a2 += __shfl_xor(a2, 32, 64);
    a3 += __shfl_xor(a3, 32, 64);
    if (half == 0) {
        us4 oh;
        oh.x = bf16rne(a0 * dn);
        oh.y = bf16rne(a1 * dn);
        oh.z = bf16rne(a2 * dn);
        oh.w = bf16rne(a3 * dn);
        ((us4*)zh)[(size_t)n * 32 + sub] = oh;
    }
}

// layer-2 agg + relu + mean-pool fused. yb pre-scaled by dinv[src] (bf16).
// 8 nodes per 512-thread block. Half-wave dual-edge + 4x unroll.
__global__ __launch_bounds__(512)
void k_agg_pool(const unsigned short* __restrict__ yb, const int* __restrict__ row_start,
                const int* __restrict__ col, const float* __restrict__ dinv,
                const float* __restrict__ bias, const int* __restrict__ batch,
                float* __restrict__ sums) {
    __shared__ float lsum[8][256];
    const int tid = threadIdx.x;
    const int wv = tid >> 6, lane = tid & 63;
    const int half = lane >> 5, sub = lane & 31;
    const int base = blockIdx.x * 8;
    const int n = base + wv;

    const bool uni = (batch[base] == batch[base + 7]);

    const us8* y8 = (const us8*)yb;
    float a[8] = {0.f, 0.f, 0.f, 0.f, 0.f, 0.f, 0.f, 0.f};
    if (half == 0) {
        us8 sv = y8[(size_t)n * 32 + sub];
        #pragma unroll
        for (int j = 0; j < 8; ++j) a[j] = bf2f(sv[j]);
    }
    int e = row_start[n] + half;
    const int e1 = row_start[n + 1];
    for (; e + 6 < e1; e += 8) {
        int s0 = col[e], s1 = col[e + 2], s2 = col[e + 4], s3 = col[e + 6];
        us8 v0 = y8[(size_t)s0 * 32 + sub];
        us8 v1 = y8[(size_t)s1 * 32 + sub];
        us8 v2 = y8[(size_t)s2 * 32 + sub];
        us8 v3 = y8[(size_t)s3 * 32 + sub];
        #pragma unroll
        for (int j = 0; j < 8; ++j)
            a[j] += (bf2f(v0[j]) + bf2f(v1[j])) + (bf2f(v2[j]) + bf2f(v3[j]));
    }
    for (; e < e1; e += 2) {
        int s = col[e];
        us8 v = y8[(size_t)s * 32 + sub];
        #pragma unroll
        for (int j = 0; j < 8; ++j) a[j] += bf2f(v[j]);
    }
    #pragma unroll
    for (int j = 0; j < 8; ++j) a[j] += __shfl_xor(a[j], 32, 64);

    if (half == 0) {
        float dn = dinv[n];
        float4 b0 = ((const float4*)bias)[sub * 2];
        float4 b1 = ((const float4*)bias)[sub * 2 + 1];
        float4 o0, o1;
        o0.x = fmaxf(a[0] * dn + b0.x, 0.f);
        o0.y = fmaxf(a[1] * dn + b0.y, 0.f);
        o0.z = fmaxf(a[2] * dn + b0.z, 0.f);
        o0.w = fmaxf(a[3] * dn + b0.w, 0.f);
        o1.x = fmaxf(a[4] * dn + b1.x, 0.f);
        o1.y = fmaxf(a[5] * dn + b1.y, 0.f);
        o1.z = fmaxf(a[6] * dn + b1.z, 0.f);
        o1.w = fmaxf(a[7] * dn + b1.w, 0.f);
        if (uni) {
            ((float4*)&lsum[wv][sub * 8])[0] = o0;
            ((float4*)&lsum[wv][sub * 8])[1] = o1;
        } else {
            int g = batch[n];
            atomicAdd(&sums[g * 256 + sub * 8 + 0], o0.x);
            atomicAdd(&sums[g * 256 + sub * 8 + 1], o0.y);
            atomicAdd(&sums[g * 256 + sub * 8 + 2], o0.z);
            atomicAdd(&sums[g * 256 + sub * 8 + 3], o0.w);
            atomicAdd(&sums[g * 256 + sub * 8 + 4], o1.x);
            atomicAdd(&sums[g * 256 + sub * 8 + 5], o1.y);
            atomicAdd(&sums[g * 256 + sub * 8 + 6], o1.z);
            atomicAdd(&sums[g * 256 + sub * 8 + 7], o1.w);
        }
    }
    __syncthreads();
    if (uni && tid < 256) {
        float v = 0.f;
        #pragma unroll
        for (int w = 0; w < 8; ++w) v += lsum[w][tid];
        atomicAdd(&sums[batch[base] * 256 + tid], v);
    }
}

// ---------------- FC ----------------

__global__ void k_final(const float* __restrict__ sums, const int* __restrict__ bounds,
                        const float* __restrict__ Wfc, const float* __restrict__ bfc,
                        float* __restrict__ out) {
    __shared__ float red[HID_DIM];
    int g = blockIdx.x;
    int c = threadIdx.x;
    float cnt = (float)(bounds[g + 1] - bounds[g]);
    float v = sums[g * HID_DIM + c] / fmaxf(cnt, 1.0f) * Wfc[c];
    red[c] = v;
    __syncthreads();
    for (int s = HID_DIM / 2; s > 0; s >>= 1) {
        if (c < s) red[c] += red[c + s];
        __syncthreads();
    }
    if (c == 0) out[g] = red[0] + bfc[0];
}

// ---------------- launch ----------------

extern "C" void kernel_launch(void* const* d_in, const int* in_sizes, int n_in,
                              void* d_out, int out_size, void* d_ws, size_t ws_size,
                              hipStream_t stream) {
    const float* x    = (const float*)d_in[0];
    const int*   ei   = (const int*)d_in[1];
    const int*   batch= (const int*)d_in[2];
    const float* W1   = (const float*)d_in[3];
    const float* b1   = (const float*)d_in[4];
    const float* W2   = (const float*)d_in[5];
    const float* b2   = (const float*)d_in[6];
    const float* Wfc  = (const float*)d_in[7];
    const float* bfc  = (const float*)d_in[8];
    float* out = (float*)d_out;

    const int* src = ei;
    const int* dst = ei + N_EDGES;

    char* ws = (char*)d_ws;
    const size_t PLANE256 = (size_t)M_PAD * 256 * 2;
    size_t off = 0;
    unsigned short* h1h = (unsigned short*)(ws + off); off += PLANE256;
    unsigned short* r1  = (unsigned short*)(ws + off); off += PLANE256;  // zh then y2b
    unsigned short* xb  = (unsigned short*)(ws + off); off += (size_t)N_NODES * 128 * 2;
    int*   deg_i     = (int*)  (ws + off); off += 200704;
    int*   cursor    = (int*)  (ws + off); off += 200704;
    float* dinv      = (float*)(ws + off); off += 200704;
    int*   row_start = (int*)  (ws + off); off += 200704;
    int*   col       = (int*)  (ws + off); off += (size_t)N_EDGES * 4;
    unsigned short* Bh1 = (unsigned short*)(ws + off); off += 65536;
    unsigned short* Bl1 = (unsigned short*)(ws + off); off += 65536;
    unsigned short* Bh2 = (unsigned short*)(ws + off); off += 131072;
    unsigned short* Bl2 = (unsigned short*)(ws + off); off += 131072;
    float* sums      = (float*)(ws + off); off += 65536;
    int*   bounds    = (int*)  (ws + off); off += 512;
    int*   blk_tot   = (int*)  (ws + off); off += 512;
    (void)ws_size; (void)in_sizes; (void)n_in; (void)out_size;

    unsigned short* zh  = r1;   // [M_PAD,128] bf16, dead after GEMM1
    unsigned short* y2b = r1;   // [M_PAD,256] bf16, written by GEMM2

    // 1. CSR build + dinv + merged prologue
    hipMemsetAsync(deg_i, 0, 2 * 200704, stream);
    k_deg_count<<<(N_EDGES + 255) / 256, 256, 0, stream>>>(dst, deg_i);
    k_scan_blk<<<SCAN_NBLK, SCAN_BLK, 0, stream>>>(deg_i, row_start, dinv, blk_tot);
    k_scan_add<<<SCAN_NBLK, SCAN_BLK, 0, stream>>>(row_start, blk_tot);
    k_csr_fill<<<(N_EDGES + 255) / 256, 256, 0, stream>>>(src, dst, row_start, cursor, col);
    k_prep<<<2048, 256, 0, stream>>>(x, xb, W1, Bh1, Bl1, W2, Bh2, Bl2, batch, bounds, sums);

    const int gemm_grid = (N_NODES + 63) / 64;  // 782

    // 2. layer 1: zh = bf16(A_hat @ x) ; h1h = bf16(relu(z @ W1 + b1))
    k_agg_x<<<N_NODES / 4, 256, 0, stream>>>(x, xb, row_start, col, dinv, zh);
    k_gemm_mfma<1><<<gemm_grid, 256, 0, stream>>>(zh, Bh1, Bl1, dinv, b1, h1h, N_NODES, IN_DIM);

    // 3. layer 2: y2b = bf16((h1 @ W2) * dinv) ; fused agg+relu+pool
    k_gemm_mfma<0><<<gemm_grid, 256, 0, stream>>>(h1h, Bh2, Bl2, dinv, b2, y2b, N_NODES, HID_DIM);
    k_agg_pool<<<N_NODES / 8, 512, 0, stream>>>(y2b, row_start, col, dinv, b2, batch, sums);

    // 4. fc
    k_final<<<N_GRAPHS, HID_DIM, 0, stream>>>(sums, bounds, Wfc, bfc, out);
}

// Round 14
// 251.902 us; speedup vs baseline: 1.6631x; 1.0289x over previous
//
#include <hip/hip_runtime.h>
#include <hip/hip_bf16.h>

#define N_NODES 50000
#define N_EDGES 800000
#define N_GRAPHS 64
#define IN_DIM 128
#define HID_DIM 256
#define M_PAD 50048   // N_NODES padded to multiple of 64 for GEMM staging

typedef short sh8 __attribute__((ext_vector_type(8)));
typedef float f4 __attribute__((ext_vector_type(4)));
typedef unsigned short us4 __attribute__((ext_vector_type(4)));
typedef unsigned short us8 __attribute__((ext_vector_type(8)));

__device__ __forceinline__ unsigned short bf16rne(float f) {
    unsigned int u = __float_as_uint(f);
    return (unsigned short)((u + 0x7FFFu + ((u >> 16) & 1u)) >> 16);
}
__device__ __forceinline__ float bf2f(unsigned short b) {
    return __uint_as_float((unsigned int)b << 16);
}
__device__ __forceinline__ void split_bf16(float f, unsigned short& h, unsigned short& l) {
    unsigned int u = __float_as_uint(f);
    unsigned int hb = (u + 0x7FFFu + ((u >> 16) & 1u)) & 0xFFFF0000u;  // RNE
    h = (unsigned short)(hb >> 16);
    float rest = f - __uint_as_float(hb);
    unsigned int u2 = __float_as_uint(rest);
    l = (unsigned short)((u2 + 0x7FFFu + ((u2 >> 16) & 1u)) >> 16);
}

// async 16B global -> LDS (direct, no VGPR round-trip)
__device__ __forceinline__ void gl2lds16(const unsigned short* g, unsigned short* l) {
    __builtin_amdgcn_global_load_lds(
        (const __attribute__((address_space(1))) void*)g,
        (__attribute__((address_space(3))) void*)l, 16, 0, 0);
}

// ---------------- merged prologue: zero deg/cursor, x->bf16, W splits, bounds, sums ----

__device__ __forceinline__ void wsplit_one(const float* __restrict__ W,
                                           unsigned short* __restrict__ Bh,
                                           unsigned short* __restrict__ Bl, int i) {
    int k = i >> 8, c = i & 255;
    unsigned short h, l;
    split_bf16(W[i], h, l);
    size_t pos = (size_t)(k >> 5) * 8192 + (size_t)(((c >> 4) * 4 + ((k >> 3) & 3)) * 128 + (c & 15) * 8 + (k & 7));
    Bh[pos] = h;
    Bl[pos] = l;
}

__global__ __launch_bounds__(256)
void k_prep(const float* __restrict__ x, unsigned short* __restrict__ xb,
            const float* __restrict__ W1, unsigned short* __restrict__ Bh1, unsigned short* __restrict__ Bl1,
            const float* __restrict__ W2, unsigned short* __restrict__ Bh2, unsigned short* __restrict__ Bl2,
            const int* __restrict__ batch, int* __restrict__ bounds, float* __restrict__ sums,
            int* __restrict__ deg_i, int* __restrict__ cursor) {
    const int T = gridDim.x * 256;
    const int gid = blockIdx.x * 256 + threadIdx.x;
    for (int i = gid; i < N_NODES; i += T) { deg_i[i] = 0; cursor[i] = 0; }
    for (int i = gid; i < N_NODES * IN_DIM / 4; i += T) {
        float4 v = ((const float4*)x)[i];
        us4 o;
        o.x = bf16rne(v.x); o.y = bf16rne(v.y); o.z = bf16rne(v.z); o.w = bf16rne(v.w);
        ((us4*)xb)[i] = o;
    }
    for (int i = gid; i < IN_DIM * 256; i += T) wsplit_one(W1, Bh1, Bl1, i);
    for (int i = gid; i < HID_DIM * 256; i += T) wsplit_one(W2, Bh2, Bl2, i);
    for (int i = gid; i < N_GRAPHS * HID_DIM; i += T) sums[i] = 0.f;
    if (gid <= N_GRAPHS) {
        int lo = 0, hi = N_NODES;
        while (lo < hi) {
            int mid = (lo + hi) >> 1;
            if (batch[mid] < gid) lo = mid + 1; else hi = mid;
        }
        bounds[gid] = lo;
    }
}

// ---------------- degree / CSR build ----------------

__global__ void k_deg_count(const int* __restrict__ dst, int* __restrict__ deg) {
    int e = blockIdx.x * blockDim.x + threadIdx.x;
    if (e < N_EDGES) atomicAdd(&deg[dst[e]], 1);
}

#define SCAN_BLK 1024
#define SCAN_NBLK ((N_NODES + SCAN_BLK - 1) / SCAN_BLK)  // 49

__global__ __launch_bounds__(SCAN_BLK)
void k_scan_blk(const int* __restrict__ deg, int* __restrict__ row_start,
                float* __restrict__ dinv, int* __restrict__ blk_tot) {
    __shared__ int tmp[SCAN_BLK];
    int t = threadIdx.x;
    int i = blockIdx.x * SCAN_BLK + t;
    int d = 0;
    if (i < N_NODES) {
        d = deg[i];
        dinv[i] = rsqrtf((float)d + 1.0f);
    }
    tmp[t] = d;
    __syncthreads();
    #pragma unroll
    for (int off = 1; off < SCAN_BLK; off <<= 1) {
        int v = (t >= off) ? tmp[t - off] : 0;
        __syncthreads();
        tmp[t] += v;
        __syncthreads();
    }
    if (i < N_NODES) row_start[i] = tmp[t] - d;
    if (t == SCAN_BLK - 1) blk_tot[blockIdx.x] = tmp[t];
}

__global__ __launch_bounds__(SCAN_BLK)
void k_scan_add(int* __restrict__ row_start, const int* __restrict__ blk_tot) {
    __shared__ int soff;
    int t = threadIdx.x;
    int bid = blockIdx.x;
    if (t < 64) {
        int v = (t < bid) ? blk_tot[t] : 0;
        #pragma unroll
        for (int m = 1; m < 64; m <<= 1) v += __shfl_xor(v, m, 64);
        if (t == 0) soff = v;
    }
    __syncthreads();
    int i = bid * SCAN_BLK + t;
    if (i < N_NODES) row_start[i] += soff;
    if (bid == 0 && t == 0) row_start[N_NODES] = N_EDGES;
}

__global__ void k_csr_fill(const int* __restrict__ src, const int* __restrict__ dst,
                           const int* __restrict__ row_start, int* __restrict__ cursor,
                           int* __restrict__ col) {
    int e = blockIdx.x * blockDim.x + threadIdx.x;
    if (e < N_EDGES) {
        int d = dst[e];
        int pos = atomicAdd(&cursor[d], 1);
        col[row_start[d] + pos] = src[e];
    }
}

// ---------------- MFMA GEMM: [M,256] = epilogue(A[M,K] @ B[K,256]) --------
// A: bf16 plane, double-buffered LDS via global_load_lds; BK=64 (2x 32-k chunks),
// ONE barrier per 64-k step. B: hi/lo fragment-major global images, read direct
// to registers (L2-resident). 2-pass: A*Bh + A*Bl.
// MODE 0: Cout = bf16(acc * dinv[m]);  MODE 1: Cout = bf16(relu(acc + bias[c]))

template<int MODE>
__global__ __launch_bounds__(256)
void k_gemm_mfma(const unsigned short* __restrict__ Ah,
                 const unsigned short* __restrict__ Bh, const unsigned short* __restrict__ Bl,
                 const float* __restrict__ dinv, const float* __restrict__ bias,
                 unsigned short* __restrict__ Cout, int M, int K) {
    __shared__ unsigned short AhL[2][2][2048];  // [dbuf][kchunk][64rows x 32k]

    const int tid = threadIdx.x;
    const int wv = tid >> 6, lane = tid & 63;
    const int m0 = blockIdx.x * 64;

    const int ar = wv * 16 + (lane & 15);
    const int kseg = lane >> 4;
    const unsigned short* aph = Ah + (size_t)(m0 + ar) * K + kseg * 8;
    const int adoff = (wv * 64 + lane) * 8;

    f4 acc[4][4];
    #pragma unroll
    for (int mi = 0; mi < 4; ++mi)
        #pragma unroll
        for (int nj = 0; nj < 4; ++nj)
            acc[mi][nj] = f4{0.f, 0.f, 0.f, 0.f};

    const int nsteps = K >> 6;  // 64-k steps
    gl2lds16(aph, &AhL[0][0][adoff]);
    gl2lds16(aph + 32, &AhL[0][1][adoff]);

    int cur = 0;
    for (int s = 0; s < nsteps; ++s) {
        __syncthreads();  // drains vmcnt -> A(s) visible
        if (s + 1 < nsteps) {
            gl2lds16(aph + (s + 1) * 64, &AhL[cur ^ 1][0][adoff]);
            gl2lds16(aph + (s + 1) * 64 + 32, &AhL[cur ^ 1][1][adoff]);
        }
        #pragma unroll
        for (int kk = 0; kk < 2; ++kk) {
            const int bstep = s * 2 + kk;
            const unsigned short* gb = Bh + (size_t)bstep * 8192 + wv * 2048 + lane * 8;
            const unsigned short* gl = Bl + (size_t)bstep * 8192 + wv * 2048 + lane * 8;
            sh8 bfh[4], bfl[4];
            #pragma unroll
            for (int nj = 0; nj < 4; ++nj) {
                bfh[nj] = *reinterpret_cast<const sh8*>(gb + nj * 512);
                bfl[nj] = *reinterpret_cast<const sh8*>(gl + nj * 512);
            }
            sh8 afh[4];
            #pragma unroll
            for (int mi = 0; mi < 4; ++mi)
                afh[mi] = *reinterpret_cast<const sh8*>(&AhL[cur][kk][mi * 512 + lane * 8]);
            #pragma unroll
            for (int mi = 0; mi < 4; ++mi) {
                #pragma unroll
                for (int nj = 0; nj < 4; ++nj) {
                    acc[mi][nj] = __builtin_amdgcn_mfma_f32_16x16x32_bf16(afh[mi], bfh[nj], acc[mi][nj], 0, 0, 0);
                    acc[mi][nj] = __builtin_amdgcn_mfma_f32_16x16x32_bf16(afh[mi], bfl[nj], acc[mi][nj], 0, 0, 0);
                }
            }
        }
        cur ^= 1;
    }

    #pragma unroll
    for (int mi = 0; mi < 4; ++mi) {
        #pragma unroll
        for (int q = 0; q < 4; ++q) {
            int grow = m0 + mi * 16 + (lane >> 4) * 4 + q;
            if (grow < M) {
                float dm = (MODE == 0) ? dinv[grow] : 0.f;
                #pragma unroll
                for (int nj = 0; nj < 4; ++nj) {
                    int gcol = wv * 64 + nj * 16 + (lane & 15);
                    float v = acc[mi][nj][q];
                    if (MODE == 0) {
                        Cout[(size_t)grow * 256 + gcol] = bf16rne(v * dm);
                    } else {
                        Cout[(size_t)grow * 256 + gcol] = bf16rne(fmaxf(v + bias[gcol], 0.f));
                    }
                }
            }
        }
    }
}

// ---------------- aggregation (round-9 proven shapes) ----------------

// layer-1: z[n] = dinv[n] * ( dinv[n]*x[n] + sum dinv[s]*xb[s] )
// Half-wave dual-edge + 4x unroll. Output: bf16 plane zh.
__global__ __launch_bounds__(256)
void k_agg_x(const float* __restrict__ x, const unsigned short* __restrict__ xb,
             const int* __restrict__ row_start, const int* __restrict__ col,
             const float* __restrict__ dinv, unsigned short* __restrict__ zh) {
    int wv = threadIdx.x >> 6, lane = threadIdx.x & 63;
    int half = lane >> 5, sub = lane & 31;
    int n = blockIdx.x * 4 + wv;

    float a0 = 0.f, a1 = 0.f, a2 = 0.f, a3 = 0.f;
    float dn = dinv[n];
    if (half == 0) {
        float4 xs = ((const float4*)x)[(size_t)n * 32 + sub];
        a0 = xs.x * dn; a1 = xs.y * dn; a2 = xs.z * dn; a3 = xs.w * dn;
    }
    const us4* xb4 = (const us4*)xb;
    int e = row_start[n] + half;
    const int e1 = row_start[n + 1];
    for (; e + 6 < e1; e += 8) {
        int s0 = col[e], s1 = col[e + 2], s2 = col[e + 4], s3 = col[e + 6];
        float d0 = dinv[s0], d1 = dinv[s1], d2 = dinv[s2], d3 = dinv[s3];
        us4 v0 = xb4[(size_t)s0 * 32 + sub];
        us4 v1 = xb4[(size_t)s1 * 32 + sub];
        us4 v2 = xb4[(size_t)s2 * 32 + sub];
        us4 v3 = xb4[(size_t)s3 * 32 + sub];
        a0 += bf2f(v0.x) * d0 + bf2f(v1.x) * d1 + bf2f(v2.x) * d2 + bf2f(v3.x) * d3;
        a1 += bf2f(v0.y) * d0 + bf2f(v1.y) * d1 + bf2f(v2.y) * d2 + bf2f(v3.y) * d3;
        a2 += bf2f(v0.z) * d0 + bf2f(v1.z) * d1 + bf2f(v2.z) * d2 + bf2f(v3.z) * d3;
        a3 += bf2f(v0.w) * d0 + bf2f(v1.w) * d1 + bf2f(v2.w) * d2 + bf2f(v3.w) * d3;
    }
    for (; e < e1; e += 2) {
        int s = col[e];
        float ds = dinv[s];
        us4 v = xb4[(size_t)s * 32 + sub];
        a0 += bf2f(v.x) * ds; a1 += bf2f(v.y) * ds;
        a2 += bf2f(v.z) * ds; a3 += bf2f(v.w) * ds;
    }
    a0 += __shfl_xor(a0, 32, 64);
    a1 += __shfl_xor(a1, 32, 64);
    a2 += __shfl_xor(a2, 32, 64);
    a3 += __shfl_xor(a3, 32, 64);
    if (half == 0) {
        us4 oh;
        oh.x = bf16rne(a0 * dn);
        oh.y = bf16rne(a1 * dn);
        oh.z = bf16rne(a2 * dn);
        oh.w = bf16rne(a3 * dn);
        ((us4*)zh)[(size_t)n * 32 + sub] = oh;
    }
}

// layer-2 agg + relu + mean-pool fused. yb pre-scaled by dinv[src] (bf16).
// 8 nodes per 512-thread block. Half-wave dual-edge + 4x unroll.
__global__ __launch_bounds__(512)
void k_agg_pool(const unsigned short* __restrict__ yb, const int* __restrict__ row_start,
                const int* __restrict__ col, const float* __restrict__ dinv,
                const float* __restrict__ bias, const int* __restrict__ batch,
                float* __restrict__ sums) {
    __shared__ float lsum[8][256];
    const int tid = threadIdx.x;
    const int wv = tid >> 6, lane = tid & 63;
    const int half = lane >> 5, sub = lane & 31;
    const int base = blockIdx.x * 8;
    const int n = base + wv;

    const bool uni = (batch[base] == batch[base + 7]);

    const us8* y8 = (const us8*)yb;
    float a[8] = {0.f, 0.f, 0.f, 0.f, 0.f, 0.f, 0.f, 0.f};
    if (half == 0) {
        us8 sv = y8[(size_t)n * 32 + sub];
        #pragma unroll
        for (int j = 0; j < 8; ++j) a[j] = bf2f(sv[j]);
    }
    int e = row_start[n] + half;
    const int e1 = row_start[n + 1];
    for (; e + 6 < e1; e += 8) {
        int s0 = col[e], s1 = col[e + 2], s2 = col[e + 4], s3 = col[e + 6];
        us8 v0 = y8[(size_t)s0 * 32 + sub];
        us8 v1 = y8[(size_t)s1 * 32 + sub];
        us8 v2 = y8[(size_t)s2 * 32 + sub];
        us8 v3 = y8[(size_t)s3 * 32 + sub];
        #pragma unroll
        for (int j = 0; j < 8; ++j)
            a[j] += (bf2f(v0[j]) + bf2f(v1[j])) + (bf2f(v2[j]) + bf2f(v3[j]));
    }
    for (; e < e1; e += 2) {
        int s = col[e];
        us8 v = y8[(size_t)s * 32 + sub];
        #pragma unroll
        for (int j = 0; j < 8; ++j) a[j] += bf2f(v[j]);
    }
    #pragma unroll
    for (int j = 0; j < 8; ++j) a[j] += __shfl_xor(a[j], 32, 64);

    if (half == 0) {
        float dn = dinv[n];
        float4 b0 = ((const float4*)bias)[sub * 2];
        float4 b1 = ((const float4*)bias)[sub * 2 + 1];
        float4 o0, o1;
        o0.x = fmaxf(a[0] * dn + b0.x, 0.f);
        o0.y = fmaxf(a[1] * dn + b0.y, 0.f);
        o0.z = fmaxf(a[2] * dn + b0.z, 0.f);
        o0.w = fmaxf(a[3] * dn + b0.w, 0.f);
        o1.x = fmaxf(a[4] * dn + b1.x, 0.f);
        o1.y = fmaxf(a[5] * dn + b1.y, 0.f);
        o1.z = fmaxf(a[6] * dn + b1.z, 0.f);
        o1.w = fmaxf(a[7] * dn + b1.w, 0.f);
        if (uni) {
            ((float4*)&lsum[wv][sub * 8])[0] = o0;
            ((float4*)&lsum[wv][sub * 8])[1] = o1;
        } else {
            int g = batch[n];
            atomicAdd(&sums[g * 256 + sub * 8 + 0], o0.x);
            atomicAdd(&sums[g * 256 + sub * 8 + 1], o0.y);
            atomicAdd(&sums[g * 256 + sub * 8 + 2], o0.z);
            atomicAdd(&sums[g * 256 + sub * 8 + 3], o0.w);
            atomicAdd(&sums[g * 256 + sub * 8 + 4], o1.x);
            atomicAdd(&sums[g * 256 + sub * 8 + 5], o1.y);
            atomicAdd(&sums[g * 256 + sub * 8 + 6], o1.z);
            atomicAdd(&sums[g * 256 + sub * 8 + 7], o1.w);
        }
    }
    __syncthreads();
    if (uni && tid < 256) {
        float v = 0.f;
        #pragma unroll
        for (int w = 0; w < 8; ++w) v += lsum[w][tid];
        atomicAdd(&sums[batch[base] * 256 + tid], v);
    }
}

// ---------------- FC ----------------

__global__ void k_final(const float* __restrict__ sums, const int* __restrict__ bounds,
                        const float* __restrict__ Wfc, const float* __restrict__ bfc,
                        float* __restrict__ out) {
    __shared__ float red[HID_DIM];
    int g = blockIdx.x;
    int c = threadIdx.x;
    float cnt = (float)(bounds[g + 1] - bounds[g]);
    float v = sums[g * HID_DIM + c] / fmaxf(cnt, 1.0f) * Wfc[c];
    red[c] = v;
    __syncthreads();
    for (int s = HID_DIM / 2; s > 0; s >>= 1) {
        if (c < s) red[c] += red[c + s];
        __syncthreads();
    }
    if (c == 0) out[g] = red[0] + bfc[0];
}

// ---------------- launch ----------------

extern "C" void kernel_launch(void* const* d_in, const int* in_sizes, int n_in,
                              void* d_out, int out_size, void* d_ws, size_t ws_size,
                              hipStream_t stream) {
    const float* x    = (const float*)d_in[0];
    const int*   ei   = (const int*)d_in[1];
    const int*   batch= (const int*)d_in[2];
    const float* W1   = (const float*)d_in[3];
    const float* b1   = (const float*)d_in[4];
    const float* W2   = (const float*)d_in[5];
    const float* b2   = (const float*)d_in[6];
    const float* Wfc  = (const float*)d_in[7];
    const float* bfc  = (const float*)d_in[8];
    float* out = (float*)d_out;

    const int* src = ei;
    const int* dst = ei + N_EDGES;

    char* ws = (char*)d_ws;
    const size_t PLANE256 = (size_t)M_PAD * 256 * 2;
    size_t off = 0;
    unsigned short* h1h = (unsigned short*)(ws + off); off += PLANE256;
    unsigned short* r1  = (unsigned short*)(ws + off); off += PLANE256;  // zh then y2b
    unsigned short* xb  = (unsigned short*)(ws + off); off += (size_t)N_NODES * 128 * 2;
    int*   deg_i     = (int*)  (ws + off); off += 200704;
    int*   cursor    = (int*)  (ws + off); off += 200704;
    float* dinv      = (float*)(ws + off); off += 200704;
    int*   row_start = (int*)  (ws + off); off += 200704;
    int*   col       = (int*)  (ws + off); off += (size_t)N_EDGES * 4;
    unsigned short* Bh1 = (unsigned short*)(ws + off); off += 65536;
    unsigned short* Bl1 = (unsigned short*)(ws + off); off += 65536;
    unsigned short* Bh2 = (unsigned short*)(ws + off); off += 131072;
    unsigned short* Bl2 = (unsigned short*)(ws + off); off += 131072;
    float* sums      = (float*)(ws + off); off += 65536;
    int*   bounds    = (int*)  (ws + off); off += 512;
    int*   blk_tot   = (int*)  (ws + off); off += 512;
    (void)ws_size; (void)in_sizes; (void)n_in; (void)out_size;

    unsigned short* zh  = r1;   // [M_PAD,128] bf16, dead after GEMM1
    unsigned short* y2b = r1;   // [M_PAD,256] bf16, written by GEMM2

    // 1. merged prologue (zeros deg/cursor too) + CSR build
    k_prep<<<2048, 256, 0, stream>>>(x, xb, W1, Bh1, Bl1, W2, Bh2, Bl2, batch, bounds, sums, deg_i, cursor);
    k_deg_count<<<(N_EDGES + 255) / 256, 256, 0, stream>>>(dst, deg_i);
    k_scan_blk<<<SCAN_NBLK, SCAN_BLK, 0, stream>>>(deg_i, row_start, dinv, blk_tot);
    k_scan_add<<<SCAN_NBLK, SCAN_BLK, 0, stream>>>(row_start, blk_tot);
    k_csr_fill<<<(N_EDGES + 255) / 256, 256, 0, stream>>>(src, dst, row_start, cursor, col);

    const int gemm_grid = (N_NODES + 63) / 64;  // 782

    // 2. layer 1: zh = bf16(A_hat @ x) ; h1h = bf16(relu(z @ W1 + b1))
    k_agg_x<<<N_NODES / 4, 256, 0, stream>>>(x, xb, row_start, col, dinv, zh);
    k_gemm_mfma<1><<<gemm_grid, 256, 0, stream>>>(zh, Bh1, Bl1, dinv, b1, h1h, N_NODES, IN_DIM);

    // 3. layer 2: y2b = bf16((h1 @ W2) * dinv) ; fused agg+relu+pool
    k_gemm_mfma<0><<<gemm_grid, 256, 0, stream>>>(h1h, Bh2, Bl2, dinv, b2, y2b, N_NODES, HID_DIM);
    k_agg_pool<<<N_NODES / 8, 512, 0, stream>>>(y2b, row_start, col, dinv, b2, batch, sums);

    // 4. fc
    k_final<<<N_GRAPHS, HID_DIM, 0, stream>>>(sums, bounds, Wfc, bfc, out);
}

// Round 15
// 248.457 us; speedup vs baseline: 1.6861x; 1.0139x over previous
//
#include <hip/hip_runtime.h>
#include <hip/hip_bf16.h>

#define N_NODES 50000
#define N_EDGES 800000
#define N_GRAPHS 64
#define IN_DIM 128
#define HID_DIM 256
#define M_PAD 50048   // N_NODES padded to multiple of 64 for GEMM staging

typedef short sh8 __attribute__((ext_vector_type(8)));
typedef float f4 __attribute__((ext_vector_type(4)));
typedef unsigned short us4 __attribute__((ext_vector_type(4)));
typedef unsigned short us8 __attribute__((ext_vector_type(8)));

__device__ __forceinline__ unsigned short bf16rne(float f) {
    unsigned int u = __float_as_uint(f);
    return (unsigned short)((u + 0x7FFFu + ((u >> 16) & 1u)) >> 16);
}
__device__ __forceinline__ float bf2f(unsigned short b) {
    return __uint_as_float((unsigned int)b << 16);
}

// async 16B global -> LDS (direct, no VGPR round-trip)
__device__ __forceinline__ void gl2lds16(const unsigned short* g, unsigned short* l) {
    __builtin_amdgcn_global_load_lds(
        (const __attribute__((address_space(1))) void*)g,
        (__attribute__((address_space(3))) void*)l, 16, 0, 0);
}

// ---------------- merged prologue: zero deg/cursor, x->bf16, W->bf16 frag-major,
//                  bounds, sums ----

// W[K x 256] -> bf16 fragment-major image:
// (k,c) -> chunk k>>5, pos = ((c>>4)*4 + ((k>>3)&3))*128 + (c&15)*8 + (k&7)
__device__ __forceinline__ void wconv_one(const float* __restrict__ W,
                                          unsigned short* __restrict__ Bh, int i) {
    int k = i >> 8, c = i & 255;
    size_t pos = (size_t)(k >> 5) * 8192 + (size_t)(((c >> 4) * 4 + ((k >> 3) & 3)) * 128 + (c & 15) * 8 + (k & 7));
    Bh[pos] = bf16rne(W[i]);
}

__global__ __launch_bounds__(256)
void k_prep(const float* __restrict__ x, unsigned short* __restrict__ xb,
            const float* __restrict__ W1, unsigned short* __restrict__ Bh1,
            const float* __restrict__ W2, unsigned short* __restrict__ Bh2,
            const int* __restrict__ batch, int* __restrict__ bounds, float* __restrict__ sums,
            int* __restrict__ deg_i, int* __restrict__ cursor) {
    const int T = gridDim.x * 256;
    const int gid = blockIdx.x * 256 + threadIdx.x;
    for (int i = gid; i < N_NODES; i += T) { deg_i[i] = 0; cursor[i] = 0; }
    for (int i = gid; i < N_NODES * IN_DIM / 4; i += T) {
        float4 v = ((const float4*)x)[i];
        us4 o;
        o.x = bf16rne(v.x); o.y = bf16rne(v.y); o.z = bf16rne(v.z); o.w = bf16rne(v.w);
        ((us4*)xb)[i] = o;
    }
    for (int i = gid; i < IN_DIM * 256; i += T) wconv_one(W1, Bh1, i);
    for (int i = gid; i < HID_DIM * 256; i += T) wconv_one(W2, Bh2, i);
    for (int i = gid; i < N_GRAPHS * HID_DIM; i += T) sums[i] = 0.f;
    if (gid <= N_GRAPHS) {
        int lo = 0, hi = N_NODES;
        while (lo < hi) {
            int mid = (lo + hi) >> 1;
            if (batch[mid] < gid) lo = mid + 1; else hi = mid;
        }
        bounds[gid] = lo;
    }
}

// ---------------- degree / CSR build ----------------

__global__ void k_deg_count(const int* __restrict__ dst, int* __restrict__ deg) {
    int e = blockIdx.x * blockDim.x + threadIdx.x;
    if (e < N_EDGES) atomicAdd(&deg[dst[e]], 1);
}

#define SCAN_BLK 1024
#define SCAN_NBLK ((N_NODES + SCAN_BLK - 1) / SCAN_BLK)  // 49

__global__ __launch_bounds__(SCAN_BLK)
void k_scan_blk(const int* __restrict__ deg, int* __restrict__ row_start,
                float* __restrict__ dinv, int* __restrict__ blk_tot) {
    __shared__ int tmp[SCAN_BLK];
    int t = threadIdx.x;
    int i = blockIdx.x * SCAN_BLK + t;
    int d = 0;
    if (i < N_NODES) {
        d = deg[i];
        dinv[i] = rsqrtf((float)d + 1.0f);
    }
    tmp[t] = d;
    __syncthreads();
    #pragma unroll
    for (int off = 1; off < SCAN_BLK; off <<= 1) {
        int v = (t >= off) ? tmp[t - off] : 0;
        __syncthreads();
        tmp[t] += v;
        __syncthreads();
    }
    if (i < N_NODES) row_start[i] = tmp[t] - d;
    if (t == SCAN_BLK - 1) blk_tot[blockIdx.x] = tmp[t];
}

__global__ __launch_bounds__(SCAN_BLK)
void k_scan_add(int* __restrict__ row_start, const int* __restrict__ blk_tot) {
    __shared__ int soff;
    int t = threadIdx.x;
    int bid = blockIdx.x;
    if (t < 64) {
        int v = (t < bid) ? blk_tot[t] : 0;
        #pragma unroll
        for (int m = 1; m < 64; m <<= 1) v += __shfl_xor(v, m, 64);
        if (t == 0) soff = v;
    }
    __syncthreads();
    int i = bid * SCAN_BLK + t;
    if (i < N_NODES) row_start[i] += soff;
    if (bid == 0 && t == 0) row_start[N_NODES] = N_EDGES;
}

__global__ void k_csr_fill(const int* __restrict__ src, const int* __restrict__ dst,
                           const int* __restrict__ row_start, int* __restrict__ cursor,
                           int* __restrict__ col) {
    int e = blockIdx.x * blockDim.x + threadIdx.x;
    if (e < N_EDGES) {
        int d = dst[e];
        int pos = atomicAdd(&cursor[d], 1);
        col[row_start[d] + pos] = src[e];
    }
}

// ---------------- MFMA GEMM: [M,256] = epilogue(A[M,K] @ B[K,256]) --------
// A: bf16 plane, double-buffered LDS via global_load_lds; BK=64, 1 barrier/step.
// B: bf16 fragment-major global image, read direct to registers (L2-resident).
// Single pass (plain bf16 weights).
// MODE 0: Cout = bf16(acc * dinv[m]);  MODE 1: Cout = bf16(relu(acc + bias[c]))

template<int MODE>
__global__ __launch_bounds__(256)
void k_gemm_mfma(const unsigned short* __restrict__ Ah,
                 const unsigned short* __restrict__ Bh,
                 const float* __restrict__ dinv, const float* __restrict__ bias,
                 unsigned short* __restrict__ Cout, int M, int K) {
    __shared__ unsigned short AhL[2][2][2048];  // [dbuf][kchunk][64rows x 32k]

    const int tid = threadIdx.x;
    const int wv = tid >> 6, lane = tid & 63;
    const int m0 = blockIdx.x * 64;

    const int ar = wv * 16 + (lane & 15);
    const int kseg = lane >> 4;
    const unsigned short* aph = Ah + (size_t)(m0 + ar) * K + kseg * 8;
    const int adoff = (wv * 64 + lane) * 8;

    f4 acc[4][4];
    #pragma unroll
    for (int mi = 0; mi < 4; ++mi)
        #pragma unroll
        for (int nj = 0; nj < 4; ++nj)
            acc[mi][nj] = f4{0.f, 0.f, 0.f, 0.f};

    const int nsteps = K >> 6;  // 64-k steps
    gl2lds16(aph, &AhL[0][0][adoff]);
    gl2lds16(aph + 32, &AhL[0][1][adoff]);

    int cur = 0;
    for (int s = 0; s < nsteps; ++s) {
        __syncthreads();  // drains vmcnt -> A(s) visible
        if (s + 1 < nsteps) {
            gl2lds16(aph + (s + 1) * 64, &AhL[cur ^ 1][0][adoff]);
            gl2lds16(aph + (s + 1) * 64 + 32, &AhL[cur ^ 1][1][adoff]);
        }
        #pragma unroll
        for (int kk = 0; kk < 2; ++kk) {
            const int bstep = s * 2 + kk;
            const unsigned short* gb = Bh + (size_t)bstep * 8192 + wv * 2048 + lane * 8;
            sh8 bfh[4];
            #pragma unroll
            for (int nj = 0; nj < 4; ++nj)
                bfh[nj] = *reinterpret_cast<const sh8*>(gb + nj * 512);
            sh8 afh[4];
            #pragma unroll
            for (int mi = 0; mi < 4; ++mi)
                afh[mi] = *reinterpret_cast<const sh8*>(&AhL[cur][kk][mi * 512 + lane * 8]);
            #pragma unroll
            for (int mi = 0; mi < 4; ++mi)
                #pragma unroll
                for (int nj = 0; nj < 4; ++nj)
                    acc[mi][nj] = __builtin_amdgcn_mfma_f32_16x16x32_bf16(afh[mi], bfh[nj], acc[mi][nj], 0, 0, 0);
        }
        cur ^= 1;
    }

    #pragma unroll
    for (int mi = 0; mi < 4; ++mi) {
        #pragma unroll
        for (int q = 0; q < 4; ++q) {
            int grow = m0 + mi * 16 + (lane >> 4) * 4 + q;
            if (grow < M) {
                float dm = (MODE == 0) ? dinv[grow] : 0.f;
                #pragma unroll
                for (int nj = 0; nj < 4; ++nj) {
                    int gcol = wv * 64 + nj * 16 + (lane & 15);
                    float v = acc[mi][nj][q];
                    if (MODE == 0) {
                        Cout[(size_t)grow * 256 + gcol] = bf16rne(v * dm);
                    } else {
                        Cout[(size_t)grow * 256 + gcol] = bf16rne(fmaxf(v + bias[gcol], 0.f));
                    }
                }
            }
        }
    }
}

// ---------------- aggregation (round-9 proven shapes) ----------------

// layer-1: z[n] = dinv[n] * ( dinv[n]*x[n] + sum dinv[s]*xb[s] )
// Half-wave dual-edge + 4x unroll. Output: bf16 plane zh.
__global__ __launch_bounds__(256)
void k_agg_x(const float* __restrict__ x, const unsigned short* __restrict__ xb,
             const int* __restrict__ row_start, const int* __restrict__ col,
             const float* __restrict__ dinv, unsigned short* __restrict__ zh) {
    int wv = threadIdx.x >> 6, lane = threadIdx.x & 63;
    int half = lane >> 5, sub = lane & 31;
    int n = blockIdx.x * 4 + wv;

    float a0 = 0.f, a1 = 0.f, a2 = 0.f, a3 = 0.f;
    float dn = dinv[n];
    if (half == 0) {
        float4 xs = ((const float4*)x)[(size_t)n * 32 + sub];
        a0 = xs.x * dn; a1 = xs.y * dn; a2 = xs.z * dn; a3 = xs.w * dn;
    }
    const us4* xb4 = (const us4*)xb;
    int e = row_start[n] + half;
    const int e1 = row_start[n + 1];
    for (; e + 6 < e1; e += 8) {
        int s0 = col[e], s1 = col[e + 2], s2 = col[e + 4], s3 = col[e + 6];
        float d0 = dinv[s0], d1 = dinv[s1], d2 = dinv[s2], d3 = dinv[s3];
        us4 v0 = xb4[(size_t)s0 * 32 + sub];
        us4 v1 = xb4[(size_t)s1 * 32 + sub];
        us4 v2 = xb4[(size_t)s2 * 32 + sub];
        us4 v3 = xb4[(size_t)s3 * 32 + sub];
        a0 += bf2f(v0.x) * d0 + bf2f(v1.x) * d1 + bf2f(v2.x) * d2 + bf2f(v3.x) * d3;
        a1 += bf2f(v0.y) * d0 + bf2f(v1.y) * d1 + bf2f(v2.y) * d2 + bf2f(v3.y) * d3;
        a2 += bf2f(v0.z) * d0 + bf2f(v1.z) * d1 + bf2f(v2.z) * d2 + bf2f(v3.z) * d3;
        a3 += bf2f(v0.w) * d0 + bf2f(v1.w) * d1 + bf2f(v2.w) * d2 + bf2f(v3.w) * d3;
    }
    for (; e < e1; e += 2) {
        int s = col[e];
        float ds = dinv[s];
        us4 v = xb4[(size_t)s * 32 + sub];
        a0 += bf2f(v.x) * ds; a1 += bf2f(v.y) * ds;
        a2 += bf2f(v.z) * ds; a3 += bf2f(v.w) * ds;
    }
    a0 += __shfl_xor(a0, 32, 64);
    a1 += __shfl_xor(a1, 32, 64);
    a2 += __shfl_xor(a2, 32, 64);
    a3 += __shfl_xor(a3, 32, 64);
    if (half == 0) {
        us4 oh;
        oh.x = bf16rne(a0 * dn);
        oh.y = bf16rne(a1 * dn);
        oh.z = bf16rne(a2 * dn);
        oh.w = bf16rne(a3 * dn);
        ((us4*)zh)[(size_t)n * 32 + sub] = oh;
    }
}

// layer-2 agg + relu + mean-pool fused. yb pre-scaled by dinv[src] (bf16).
// 8 nodes per 512-thread block. Half-wave dual-edge + 4x unroll.
__global__ __launch_bounds__(512)
void k_agg_pool(const unsigned short* __restrict__ yb, const int* __restrict__ row_start,
                const int* __restrict__ col, const float* __restrict__ dinv,
                const float* __restrict__ bias, const int* __restrict__ batch,
                float* __restrict__ sums) {
    __shared__ float lsum[8][256];
    const int tid = threadIdx.x;
    const int wv = tid >> 6, lane = tid & 63;
    const int half = lane >> 5, sub = lane & 31;
    const int base = blockIdx.x * 8;
    const int n = base + wv;

    const bool uni = (batch[base] == batch[base + 7]);

    const us8* y8 = (const us8*)yb;
    float a[8] = {0.f, 0.f, 0.f, 0.f, 0.f, 0.f, 0.f, 0.f};
    if (half == 0) {
        us8 sv = y8[(size_t)n * 32 + sub];
        #pragma unroll
        for (int j = 0; j < 8; ++j) a[j] = bf2f(sv[j]);
    }
    int e = row_start[n] + half;
    const int e1 = row_start[n + 1];
    for (; e + 6 < e1; e += 8) {
        int s0 = col[e], s1 = col[e + 2], s2 = col[e + 4], s3 = col[e + 6];
        us8 v0 = y8[(size_t)s0 * 32 + sub];
        us8 v1 = y8[(size_t)s1 * 32 + sub];
        us8 v2 = y8[(size_t)s2 * 32 + sub];
        us8 v3 = y8[(size_t)s3 * 32 + sub];
        #pragma unroll
        for (int j = 0; j < 8; ++j)
            a[j] += (bf2f(v0[j]) + bf2f(v1[j])) + (bf2f(v2[j]) + bf2f(v3[j]));
    }
    for (; e < e1; e += 2) {
        int s = col[e];
        us8 v = y8[(size_t)s * 32 + sub];
        #pragma unroll
        for (int j = 0; j < 8; ++j) a[j] += bf2f(v[j]);
    }
    #pragma unroll
    for (int j = 0; j < 8; ++j) a[j] += __shfl_xor(a[j], 32, 64);

    if (half == 0) {
        float dn = dinv[n];
        float4 b0 = ((const float4*)bias)[sub * 2];
        float4 b1 = ((const float4*)bias)[sub * 2 + 1];
        float4 o0, o1;
        o0.x = fmaxf(a[0] * dn + b0.x, 0.f);
        o0.y = fmaxf(a[1] * dn + b0.y, 0.f);
        o0.z = fmaxf(a[2] * dn + b0.z, 0.f);
        o0.w = fmaxf(a[3] * dn + b0.w, 0.f);
        o1.x = fmaxf(a[4] * dn + b1.x, 0.f);
        o1.y = fmaxf(a[5] * dn + b1.y, 0.f);
        o1.z = fmaxf(a[6] * dn + b1.z, 0.f);
        o1.w = fmaxf(a[7] * dn + b1.w, 0.f);
        if (uni) {
            ((float4*)&lsum[wv][sub * 8])[0] = o0;
            ((float4*)&lsum[wv][sub * 8])[1] = o1;
        } else {
            int g = batch[n];
            atomicAdd(&sums[g * 256 + sub * 8 + 0], o0.x);
            atomicAdd(&sums[g * 256 + sub * 8 + 1], o0.y);
            atomicAdd(&sums[g * 256 + sub * 8 + 2], o0.z);
            atomicAdd(&sums[g * 256 + sub * 8 + 3], o0.w);
            atomicAdd(&sums[g * 256 + sub * 8 + 4], o1.x);
            atomicAdd(&sums[g * 256 + sub * 8 + 5], o1.y);
            atomicAdd(&sums[g * 256 + sub * 8 + 6], o1.z);
            atomicAdd(&sums[g * 256 + sub * 8 + 7], o1.w);
        }
    }
    __syncthreads();
    if (uni && tid < 256) {
        float v = 0.f;
        #pragma unroll
        for (int w = 0; w < 8; ++w) v += lsum[w][tid];
        atomicAdd(&sums[batch[base] * 256 + tid], v);
    }
}

// ---------------- FC ----------------

__global__ void k_final(const float* __restrict__ sums, const int* __restrict__ bounds,
                        const float* __restrict__ Wfc, const float* __restrict__ bfc,
                        float* __restrict__ out) {
    __shared__ float red[HID_DIM];
    int g = blockIdx.x;
    int c = threadIdx.x;
    float cnt = (float)(bounds[g + 1] - bounds[g]);
    float v = sums[g * HID_DIM + c] / fmaxf(cnt, 1.0f) * Wfc[c];
    red[c] = v;
    __syncthreads();
    for (int s = HID_DIM / 2; s > 0; s >>= 1) {
        if (c < s) red[c] += red[c + s];
        __syncthreads();
    }
    if (c == 0) out[g] = red[0] + bfc[0];
}

// ---------------- launch ----------------

extern "C" void kernel_launch(void* const* d_in, const int* in_sizes, int n_in,
                              void* d_out, int out_size, void* d_ws, size_t ws_size,
                              hipStream_t stream) {
    const float* x    = (const float*)d_in[0];
    const int*   ei   = (const int*)d_in[1];
    const int*   batch= (const int*)d_in[2];
    const float* W1   = (const float*)d_in[3];
    const float* b1   = (const float*)d_in[4];
    const float* W2   = (const float*)d_in[5];
    const float* b2   = (const float*)d_in[6];
    const float* Wfc  = (const float*)d_in[7];
    const float* bfc  = (const float*)d_in[8];
    float* out = (float*)d_out;

    const int* src = ei;
    const int* dst = ei + N_EDGES;

    char* ws = (char*)d_ws;
    const size_t PLANE256 = (size_t)M_PAD * 256 * 2;
    size_t off = 0;
    unsigned short* h1h = (unsigned short*)(ws + off); off += PLANE256;
    unsigned short* r1  = (unsigned short*)(ws + off); off += PLANE256;  // zh then y2b
    unsigned short* xb  = (unsigned short*)(ws + off); off += (size_t)N_NODES * 128 * 2;
    int*   deg_i     = (int*)  (ws + off); off += 200704;
    int*   cursor    = (int*)  (ws + off); off += 200704;
    float* dinv      = (float*)(ws + off); off += 200704;
    int*   row_start = (int*)  (ws + off); off += 200704;
    int*   col       = (int*)  (ws + off); off += (size_t)N_EDGES * 4;
    unsigned short* Bh1 = (unsigned short*)(ws + off); off += 65536;
    unsigned short* Bh2 = (unsigned short*)(ws + off); off += 131072;
    float* sums      = (float*)(ws + off); off += 65536;
    int*   bounds    = (int*)  (ws + off); off += 512;
    int*   blk_tot   = (int*)  (ws + off); off += 512;
    (void)ws_size; (void)in_sizes; (void)n_in; (void)out_size;

    unsigned short* zh  = r1;   // [M_PAD,128] bf16, dead after GEMM1
    unsigned short* y2b = r1;   // [M_PAD,256] bf16, written by GEMM2

    // 1. merged prologue (zeros deg/cursor too) + CSR build
    k_prep<<<2048, 256, 0, stream>>>(x, xb, W1, Bh1, W2, Bh2, batch, bounds, sums, deg_i, cursor);
    k_deg_count<<<(N_EDGES + 255) / 256, 256, 0, stream>>>(dst, deg_i);
    k_scan_blk<<<SCAN_NBLK, SCAN_BLK, 0, stream>>>(deg_i, row_start, dinv, blk_tot);
    k_scan_add<<<SCAN_NBLK, SCAN_BLK, 0, stream>>>(row_start, blk_tot);
    k_csr_fill<<<(N_EDGES + 255) / 256, 256, 0, stream>>>(src, dst, row_start, cursor, col);

    const int gemm_grid = (N_NODES + 63) / 64;  // 782

    // 2. layer 1: zh = bf16(A_hat @ x) ; h1h = bf16(relu(z @ W1 + b1))
    k_agg_x<<<N_NODES / 4, 256, 0, stream>>>(x, xb, row_start, col, dinv, zh);
    k_gemm_mfma<1><<<gemm_grid, 256, 0, stream>>>(zh, Bh1, dinv, b1, h1h, N_NODES, IN_DIM);

    // 3. layer 2: y2b = bf16((h1 @ W2) * dinv) ; fused agg+relu+pool
    k_gemm_mfma<0><<<gemm_grid, 256, 0, stream>>>(h1h, Bh2, dinv, b2, y2b, N_NODES, HID_DIM);
    k_agg_pool<<<N_NODES / 8, 512, 0, stream>>>(y2b, row_start, col, dinv, b2, batch, sums);

    // 4. fc
    k_final<<<N_GRAPHS, HID_DIM, 0, stream>>>(sums, bounds, Wfc, bfc, out);
}

// Round 16
// 229.407 us; speedup vs baseline: 1.8261x; 1.0830x over previous
//
#include <hip/hip_runtime.h>
#include <hip/hip_bf16.h>

#define N_NODES 50000
#define N_EDGES 800000
#define N_GRAPHS 64
#define IN_DIM 128
#define HID_DIM 256
#define M_PAD 50048   // N_NODES padded to multiple of 64 for GEMM staging

typedef short sh8 __attribute__((ext_vector_type(8)));
typedef float f4 __attribute__((ext_vector_type(4)));
typedef float f2 __attribute__((ext_vector_type(2)));
typedef unsigned short us4 __attribute__((ext_vector_type(4)));
typedef unsigned short us8 __attribute__((ext_vector_type(8)));

__device__ __forceinline__ unsigned short bf16rne(float f) {
    unsigned int u = __float_as_uint(f);
    return (unsigned short)((u + 0x7FFFu + ((u >> 16) & 1u)) >> 16);
}
__device__ __forceinline__ float bf2f(unsigned short b) {
    return __uint_as_float((unsigned int)b << 16);
}
// f32 -> fp8 e4m3 (OCP), HW convert (RNE+sat)
__device__ __forceinline__ unsigned char f32_to_fp8(float v) {
    int p = __builtin_amdgcn_cvt_pk_fp8_f32(v, v, 0, false);
    return (unsigned char)(p & 0xFF);
}

// async 16B global -> LDS (direct, no VGPR round-trip)
__device__ __forceinline__ void gl2lds16(const unsigned short* g, unsigned short* l) {
    __builtin_amdgcn_global_load_lds(
        (const __attribute__((address_space(1))) void*)g,
        (__attribute__((address_space(3))) void*)l, 16, 0, 0);
}

// ---------------- merged prologue ----------------

__device__ __forceinline__ void wconv_one(const float* __restrict__ W,
                                          unsigned short* __restrict__ Bh, int i) {
    int k = i >> 8, c = i & 255;
    size_t pos = (size_t)(k >> 5) * 8192 + (size_t)(((c >> 4) * 4 + ((k >> 3) & 3)) * 128 + (c & 15) * 8 + (k & 7));
    Bh[pos] = bf16rne(W[i]);
}

__global__ __launch_bounds__(256)
void k_prep(const float* __restrict__ x, unsigned short* __restrict__ xb,
            const float* __restrict__ W1, unsigned short* __restrict__ Bh1,
            const float* __restrict__ W2, unsigned short* __restrict__ Bh2,
            const int* __restrict__ batch, int* __restrict__ bounds, float* __restrict__ sums,
            int* __restrict__ deg_i, int* __restrict__ cursor) {
    const int T = gridDim.x * 256;
    const int gid = blockIdx.x * 256 + threadIdx.x;
    for (int i = gid; i < N_NODES; i += T) { deg_i[i] = 0; cursor[i] = 0; }
    for (int i = gid; i < N_NODES * IN_DIM / 4; i += T) {
        float4 v = ((const float4*)x)[i];
        us4 o;
        o.x = bf16rne(v.x); o.y = bf16rne(v.y); o.z = bf16rne(v.z); o.w = bf16rne(v.w);
        ((us4*)xb)[i] = o;
    }
    for (int i = gid; i < IN_DIM * 256; i += T) wconv_one(W1, Bh1, i);
    for (int i = gid; i < HID_DIM * 256; i += T) wconv_one(W2, Bh2, i);
    for (int i = gid; i < N_GRAPHS * HID_DIM; i += T) sums[i] = 0.f;
    if (gid <= N_GRAPHS) {
        int lo = 0, hi = N_NODES;
        while (lo < hi) {
            int mid = (lo + hi) >> 1;
            if (batch[mid] < gid) lo = mid + 1; else hi = mid;
        }
        bounds[gid] = lo;
    }
}

// ---------------- degree / CSR build ----------------

__global__ void k_deg_count(const int* __restrict__ dst, int* __restrict__ deg) {
    int e = blockIdx.x * blockDim.x + threadIdx.x;
    if (e < N_EDGES) atomicAdd(&deg[dst[e]], 1);
}

#define SCAN_BLK 1024
#define SCAN_NBLK ((N_NODES + SCAN_BLK - 1) / SCAN_BLK)  // 49

__global__ __launch_bounds__(SCAN_BLK)
void k_scan_blk(const int* __restrict__ deg, int* __restrict__ row_start,
                float* __restrict__ dinv, int* __restrict__ blk_tot) {
    __shared__ int tmp[SCAN_BLK];
    int t = threadIdx.x;
    int i = blockIdx.x * SCAN_BLK + t;
    int d = 0;
    if (i < N_NODES) {
        d = deg[i];
        dinv[i] = rsqrtf((float)d + 1.0f);
    }
    tmp[t] = d;
    __syncthreads();
    #pragma unroll
    for (int off = 1; off < SCAN_BLK; off <<= 1) {
        int v = (t >= off) ? tmp[t - off] : 0;
        __syncthreads();
        tmp[t] += v;
        __syncthreads();
    }
    if (i < N_NODES) row_start[i] = tmp[t] - d;
    if (t == SCAN_BLK - 1) blk_tot[blockIdx.x] = tmp[t];
}

__global__ __launch_bounds__(SCAN_BLK)
void k_scan_add(int* __restrict__ row_start, const int* __restrict__ blk_tot) {
    __shared__ int soff;
    int t = threadIdx.x;
    int bid = blockIdx.x;
    if (t < 64) {
        int v = (t < bid) ? blk_tot[t] : 0;
        #pragma unroll
        for (int m = 1; m < 64; m <<= 1) v += __shfl_xor(v, m, 64);
        if (t == 0) soff = v;
    }
    __syncthreads();
    int i = bid * SCAN_BLK + t;
    if (i < N_NODES) row_start[i] += soff;
    if (bid == 0 && t == 0) row_start[N_NODES] = N_EDGES;
}

__global__ void k_csr_fill(const int* __restrict__ src, const int* __restrict__ dst,
                           const int* __restrict__ row_start, int* __restrict__ cursor,
                           int* __restrict__ col) {
    int e = blockIdx.x * blockDim.x + threadIdx.x;
    if (e < N_EDGES) {
        int d = dst[e];
        int pos = atomicAdd(&cursor[d], 1);
        col[row_start[d] + pos] = src[e];
    }
}

// ---------------- MFMA GEMM: [M,256] = epilogue(A[M,K] @ B[K,256]) --------
// A: bf16 plane, double-buffered LDS via global_load_lds; BK=64, 1 barrier/step.
// B: bf16 fragment-major global image, read direct to registers (L2-resident).
// MODE 0: Cf8 = fp8(acc * dinv[m] * 16)   (fp8 gather plane, x16 pre-scale)
// MODE 1: Cbf = bf16(relu(acc + bias[c]))

template<int MODE>
__global__ __launch_bounds__(256)
void k_gemm_mfma(const unsigned short* __restrict__ Ah,
                 const unsigned short* __restrict__ Bh,
                 const float* __restrict__ dinv, const float* __restrict__ bias,
                 unsigned short* __restrict__ Cbf, unsigned char* __restrict__ Cf8,
                 int M, int K) {
    __shared__ unsigned short AhL[2][2][2048];  // [dbuf][kchunk][64rows x 32k]

    const int tid = threadIdx.x;
    const int wv = tid >> 6, lane = tid & 63;
    const int m0 = blockIdx.x * 64;

    const int ar = wv * 16 + (lane & 15);
    const int kseg = lane >> 4;
    const unsigned short* aph = Ah + (size_t)(m0 + ar) * K + kseg * 8;
    const int adoff = (wv * 64 + lane) * 8;

    f4 acc[4][4];
    #pragma unroll
    for (int mi = 0; mi < 4; ++mi)
        #pragma unroll
        for (int nj = 0; nj < 4; ++nj)
            acc[mi][nj] = f4{0.f, 0.f, 0.f, 0.f};

    const int nsteps = K >> 6;  // 64-k steps
    gl2lds16(aph, &AhL[0][0][adoff]);
    gl2lds16(aph + 32, &AhL[0][1][adoff]);

    int cur = 0;
    for (int s = 0; s < nsteps; ++s) {
        __syncthreads();  // drains vmcnt -> A(s) visible
        if (s + 1 < nsteps) {
            gl2lds16(aph + (s + 1) * 64, &AhL[cur ^ 1][0][adoff]);
            gl2lds16(aph + (s + 1) * 64 + 32, &AhL[cur ^ 1][1][adoff]);
        }
        #pragma unroll
        for (int kk = 0; kk < 2; ++kk) {
            const int bstep = s * 2 + kk;
            const unsigned short* gb = Bh + (size_t)bstep * 8192 + wv * 2048 + lane * 8;
            sh8 bfh[4];
            #pragma unroll
            for (int nj = 0; nj < 4; ++nj)
                bfh[nj] = *reinterpret_cast<const sh8*>(gb + nj * 512);
            sh8 afh[4];
            #pragma unroll
            for (int mi = 0; mi < 4; ++mi)
                afh[mi] = *reinterpret_cast<const sh8*>(&AhL[cur][kk][mi * 512 + lane * 8]);
            #pragma unroll
            for (int mi = 0; mi < 4; ++mi)
                #pragma unroll
                for (int nj = 0; nj < 4; ++nj)
                    acc[mi][nj] = __builtin_amdgcn_mfma_f32_16x16x32_bf16(afh[mi], bfh[nj], acc[mi][nj], 0, 0, 0);
        }
        cur ^= 1;
    }

    #pragma unroll
    for (int mi = 0; mi < 4; ++mi) {
        #pragma unroll
        for (int q = 0; q < 4; ++q) {
            int grow = m0 + mi * 16 + (lane >> 4) * 4 + q;
            if (grow < M) {
                float dm16 = (MODE == 0) ? dinv[grow] * 16.f : 0.f;
                #pragma unroll
                for (int nj = 0; nj < 4; ++nj) {
                    int gcol = wv * 64 + nj * 16 + (lane & 15);
                    float v = acc[mi][nj][q];
                    if (MODE == 0) {
                        Cf8[(size_t)grow * 256 + gcol] = f32_to_fp8(v * dm16);
                    } else {
                        Cbf[(size_t)grow * 256 + gcol] = bf16rne(fmaxf(v + bias[gcol], 0.f));
                    }
                }
            }
        }
    }
}

// ---------------- aggregation ----------------

// layer-1: z[n] = dinv[n] * ( dinv[n]*x[n] + sum dinv[s]*xb[s] )
// Half-wave dual-edge + 4x unroll. Output: bf16 plane zh.
__global__ __launch_bounds__(256)
void k_agg_x(const float* __restrict__ x, const unsigned short* __restrict__ xb,
             const int* __restrict__ row_start, const int* __restrict__ col,
             const float* __restrict__ dinv, unsigned short* __restrict__ zh) {
    int wv = threadIdx.x >> 6, lane = threadIdx.x & 63;
    int half = lane >> 5, sub = lane & 31;
    int n = blockIdx.x * 4 + wv;

    float a0 = 0.f, a1 = 0.f, a2 = 0.f, a3 = 0.f;
    float dn = dinv[n];
    if (half == 0) {
        float4 xs = ((const float4*)x)[(size_t)n * 32 + sub];
        a0 = xs.x * dn; a1 = xs.y * dn; a2 = xs.z * dn; a3 = xs.w * dn;
    }
    const us4* xb4 = (const us4*)xb;
    int e = row_start[n] + half;
    const int e1 = row_start[n + 1];
    for (; e + 6 < e1; e += 8) {
        int s0 = col[e], s1 = col[e + 2], s2 = col[e + 4], s3 = col[e + 6];
        float d0 = dinv[s0], d1 = dinv[s1], d2 = dinv[s2], d3 = dinv[s3];
        us4 v0 = xb4[(size_t)s0 * 32 + sub];
        us4 v1 = xb4[(size_t)s1 * 32 + sub];
        us4 v2 = xb4[(size_t)s2 * 32 + sub];
        us4 v3 = xb4[(size_t)s3 * 32 + sub];
        a0 += bf2f(v0.x) * d0 + bf2f(v1.x) * d1 + bf2f(v2.x) * d2 + bf2f(v3.x) * d3;
        a1 += bf2f(v0.y) * d0 + bf2f(v1.y) * d1 + bf2f(v2.y) * d2 + bf2f(v3.y) * d3;
        a2 += bf2f(v0.z) * d0 + bf2f(v1.z) * d1 + bf2f(v2.z) * d2 + bf2f(v3.z) * d3;
        a3 += bf2f(v0.w) * d0 + bf2f(v1.w) * d1 + bf2f(v2.w) * d2 + bf2f(v3.w) * d3;
    }
    for (; e < e1; e += 2) {
        int s = col[e];
        float ds = dinv[s];
        us4 v = xb4[(size_t)s * 32 + sub];
        a0 += bf2f(v.x) * ds; a1 += bf2f(v.y) * ds;
        a2 += bf2f(v.z) * ds; a3 += bf2f(v.w) * ds;
    }
    a0 += __shfl_xor(a0, 32, 64);
    a1 += __shfl_xor(a1, 32, 64);
    a2 += __shfl_xor(a2, 32, 64);
    a3 += __shfl_xor(a3, 32, 64);
    if (half == 0) {
        us4 oh;
        oh.x = bf16rne(a0 * dn);
        oh.y = bf16rne(a1 * dn);
        oh.z = bf16rne(a2 * dn);
        oh.w = bf16rne(a3 * dn);
        ((us4*)zh)[(size_t)n * 32 + sub] = oh;
    }
}

// layer-2 agg + relu + mean-pool fused. yb = fp8(y2*16), pre-scaled by dinv[src].
// 8 nodes per 512-thread block. Half-wave dual-edge + 4x unroll.
// Row = 256 fp8 = 256B; half-wave of 32 lanes x 8B (uint2) covers it.
__global__ __launch_bounds__(512)
void k_agg_pool(const unsigned char* __restrict__ yb, const int* __restrict__ row_start,
                const int* __restrict__ col, const float* __restrict__ dinv,
                const float* __restrict__ bias, const int* __restrict__ batch,
                float* __restrict__ sums) {
    __shared__ float lsum[8][256];
    const int tid = threadIdx.x;
    const int wv = tid >> 6, lane = tid & 63;
    const int half = lane >> 5, sub = lane & 31;
    const int base = blockIdx.x * 8;
    const int n = base + wv;

    const bool uni = (batch[base] == batch[base + 7]);

    const uint2* y8 = (const uint2*)yb;   // 8 fp8 per element
    float a[8] = {0.f, 0.f, 0.f, 0.f, 0.f, 0.f, 0.f, 0.f};
    if (half == 0) {
        uint2 w = y8[(size_t)n * 32 + sub];
        f2 p0 = __builtin_amdgcn_cvt_pk_f32_fp8(w.x, false);
        f2 p1 = __builtin_amdgcn_cvt_pk_f32_fp8(w.x, true);
        f2 p2 = __builtin_amdgcn_cvt_pk_f32_fp8(w.y, false);
        f2 p3 = __builtin_amdgcn_cvt_pk_f32_fp8(w.y, true);
        a[0] = p0.x; a[1] = p0.y; a[2] = p1.x; a[3] = p1.y;
        a[4] = p2.x; a[5] = p2.y; a[6] = p3.x; a[7] = p3.y;
    }
    int e = row_start[n] + half;
    const int e1 = row_start[n + 1];
    for (; e + 6 < e1; e += 8) {
        int s0 = col[e], s1 = col[e + 2], s2 = col[e + 4], s3 = col[e + 6];
        uint2 w0 = y8[(size_t)s0 * 32 + sub];
        uint2 w1 = y8[(size_t)s1 * 32 + sub];
        uint2 w2 = y8[(size_t)s2 * 32 + sub];
        uint2 w3 = y8[(size_t)s3 * 32 + sub];
        #pragma unroll
        for (int k = 0; k < 4; ++k) {
            unsigned int wx = (k == 0) ? w0.x : (k == 1) ? w1.x : (k == 2) ? w2.x : w3.x;
            unsigned int wy = (k == 0) ? w0.y : (k == 1) ? w1.y : (k == 2) ? w2.y : w3.y;
            f2 p0 = __builtin_amdgcn_cvt_pk_f32_fp8(wx, false);
            f2 p1 = __builtin_amdgcn_cvt_pk_f32_fp8(wx, true);
            f2 p2 = __builtin_amdgcn_cvt_pk_f32_fp8(wy, false);
            f2 p3 = __builtin_amdgcn_cvt_pk_f32_fp8(wy, true);
            a[0] += p0.x; a[1] += p0.y; a[2] += p1.x; a[3] += p1.y;
            a[4] += p2.x; a[5] += p2.y; a[6] += p3.x; a[7] += p3.y;
        }
    }
    for (; e < e1; e += 2) {
        int s = col[e];
        uint2 w = y8[(size_t)s * 32 + sub];
        f2 p0 = __builtin_amdgcn_cvt_pk_f32_fp8(w.x, false);
        f2 p1 = __builtin_amdgcn_cvt_pk_f32_fp8(w.x, true);
        f2 p2 = __builtin_amdgcn_cvt_pk_f32_fp8(w.y, false);
        f2 p3 = __builtin_amdgcn_cvt_pk_f32_fp8(w.y, true);
        a[0] += p0.x; a[1] += p0.y; a[2] += p1.x; a[3] += p1.y;
        a[4] += p2.x; a[5] += p2.y; a[6] += p3.x; a[7] += p3.y;
    }
    #pragma unroll
    for (int j = 0; j < 8; ++j) a[j] += __shfl_xor(a[j], 32, 64);

    if (half == 0) {
        float dn = dinv[n] * 0.0625f;   // undo x16 fp8 pre-scale
        float4 b0 = ((const float4*)bias)[sub * 2];
        float4 b1 = ((const float4*)bias)[sub * 2 + 1];
        float4 o0, o1;
        o0.x = fmaxf(a[0] * dn + b0.x, 0.f);
        o0.y = fmaxf(a[1] * dn + b0.y, 0.f);
        o0.z = fmaxf(a[2] * dn + b0.z, 0.f);
        o0.w = fmaxf(a[3] * dn + b0.w, 0.f);
        o1.x = fmaxf(a[4] * dn + b1.x, 0.f);
        o1.y = fmaxf(a[5] * dn + b1.y, 0.f);
        o1.z = fmaxf(a[6] * dn + b1.z, 0.f);
        o1.w = fmaxf(a[7] * dn + b1.w, 0.f);
        if (uni) {
            ((float4*)&lsum[wv][sub * 8])[0] = o0;
            ((float4*)&lsum[wv][sub * 8])[1] = o1;
        } else {
            int g = batch[n];
            atomicAdd(&sums[g * 256 + sub * 8 + 0], o0.x);
            atomicAdd(&sums[g * 256 + sub * 8 + 1], o0.y);
            atomicAdd(&sums[g * 256 + sub * 8 + 2], o0.z);
            atomicAdd(&sums[g * 256 + sub * 8 + 3], o0.w);
            atomicAdd(&sums[g * 256 + sub * 8 + 4], o1.x);
            atomicAdd(&sums[g * 256 + sub * 8 + 5], o1.y);
            atomicAdd(&sums[g * 256 + sub * 8 + 6], o1.z);
            atomicAdd(&sums[g * 256 + sub * 8 + 7], o1.w);
        }
    }
    __syncthreads();
    if (uni && tid < 256) {
        float v = 0.f;
        #pragma unroll
        for (int w = 0; w < 8; ++w) v += lsum[w][tid];
        atomicAdd(&sums[batch[base] * 256 + tid], v);
    }
}

// ---------------- FC ----------------

__global__ void k_final(const float* __restrict__ sums, const int* __restrict__ bounds,
                        const float* __restrict__ Wfc, const float* __restrict__ bfc,
                        float* __restrict__ out) {
    __shared__ float red[HID_DIM];
    int g = blockIdx.x;
    int c = threadIdx.x;
    float cnt = (float)(bounds[g + 1] - bounds[g]);
    float v = sums[g * HID_DIM + c] / fmaxf(cnt, 1.0f) * Wfc[c];
    red[c] = v;
    __syncthreads();
    for (int s = HID_DIM / 2; s > 0; s >>= 1) {
        if (c < s) red[c] += red[c + s];
        __syncthreads();
    }
    if (c == 0) out[g] = red[0] + bfc[0];
}

// ---------------- launch ----------------

extern "C" void kernel_launch(void* const* d_in, const int* in_sizes, int n_in,
                              void* d_out, int out_size, void* d_ws, size_t ws_size,
                              hipStream_t stream) {
    const float* x    = (const float*)d_in[0];
    const int*   ei   = (const int*)d_in[1];
    const int*   batch= (const int*)d_in[2];
    const float* W1   = (const float*)d_in[3];
    const float* b1   = (const float*)d_in[4];
    const float* W2   = (const float*)d_in[5];
    const float* b2   = (const float*)d_in[6];
    const float* Wfc  = (const float*)d_in[7];
    const float* bfc  = (const float*)d_in[8];
    float* out = (float*)d_out;

    const int* src = ei;
    const int* dst = ei + N_EDGES;

    char* ws = (char*)d_ws;
    const size_t PLANE256 = (size_t)M_PAD * 256 * 2;
    size_t off = 0;
    unsigned short* h1h = (unsigned short*)(ws + off); off += PLANE256;
    char*           r1  = (char*)(ws + off); off += PLANE256;  // zh then y2f8
    unsigned short* xb  = (unsigned short*)(ws + off); off += (size_t)N_NODES * 128 * 2;
    int*   deg_i     = (int*)  (ws + off); off += 200704;
    int*   cursor    = (int*)  (ws + off); off += 200704;
    float* dinv      = (float*)(ws + off); off += 200704;
    int*   row_start = (int*)  (ws + off); off += 200704;
    int*   col       = (int*)  (ws + off); off += (size_t)N_EDGES * 4;
    unsigned short* Bh1 = (unsigned short*)(ws + off); off += 65536;
    unsigned short* Bh2 = (unsigned short*)(ws + off); off += 131072;
    float* sums      = (float*)(ws + off); off += 65536;
    int*   bounds    = (int*)  (ws + off); off += 512;
    int*   blk_tot   = (int*)  (ws + off); off += 512;
    (void)ws_size; (void)in_sizes; (void)n_in; (void)out_size;

    unsigned short* zh   = (unsigned short*)r1;  // [M_PAD,128] bf16, dead after GEMM1
    unsigned char*  y2f8 = (unsigned char*)r1;   // [M_PAD,256] fp8, written by GEMM2

    // 1. merged prologue (zeros deg/cursor too) + CSR build
    k_prep<<<2048, 256, 0, stream>>>(x, xb, W1, Bh1, W2, Bh2, batch, bounds, sums, deg_i, cursor);
    k_deg_count<<<(N_EDGES + 255) / 256, 256, 0, stream>>>(dst, deg_i);
    k_scan_blk<<<SCAN_NBLK, SCAN_BLK, 0, stream>>>(deg_i, row_start, dinv, blk_tot);
    k_scan_add<<<SCAN_NBLK, SCAN_BLK, 0, stream>>>(row_start, blk_tot);
    k_csr_fill<<<(N_EDGES + 255) / 256, 256, 0, stream>>>(src, dst, row_start, cursor, col);

    const int gemm_grid = (N_NODES + 63) / 64;  // 782

    // 2. layer 1: zh = bf16(A_hat @ x) ; h1h = bf16(relu(z @ W1 + b1))
    k_agg_x<<<N_NODES / 4, 256, 0, stream>>>(x, xb, row_start, col, dinv, zh);
    k_gemm_mfma<1><<<gemm_grid, 256, 0, stream>>>(zh, Bh1, dinv, b1, h1h, nullptr, N_NODES, IN_DIM);

    // 3. layer 2: y2f8 = fp8((h1 @ W2) * dinv * 16) ; fused agg+relu+pool
    k_gemm_mfma<0><<<gemm_grid, 256, 0, stream>>>(h1h, Bh2, dinv, b2, nullptr, y2f8, N_NODES, HID_DIM);
    k_agg_pool<<<N_NODES / 8, 512, 0, stream>>>(y2f8, row_start, col, dinv, b2, batch, sums);

    // 4. fc
    k_final<<<N_GRAPHS, HID_DIM, 0, stream>>>(sums, bounds, Wfc, bfc, out);
}

// Round 17
// 221.604 us; speedup vs baseline: 1.8904x; 1.0352x over previous
//
#include <hip/hip_runtime.h>
#include <hip/hip_bf16.h>

#define N_NODES 50000
#define N_EDGES 800000
#define N_GRAPHS 64
#define IN_DIM 128
#define HID_DIM 256
#define M_PAD 50048   // N_NODES padded to multiple of 64 for GEMM staging

typedef short sh8 __attribute__((ext_vector_type(8)));
typedef float f4 __attribute__((ext_vector_type(4)));
typedef float f2 __attribute__((ext_vector_type(2)));
typedef unsigned short us4 __attribute__((ext_vector_type(4)));

__device__ __forceinline__ unsigned short bf16rne(float f) {
    unsigned int u = __float_as_uint(f);
    return (unsigned short)((u + 0x7FFFu + ((u >> 16) & 1u)) >> 16);
}
__device__ __forceinline__ float bf2f(unsigned short b) {
    return __uint_as_float((unsigned int)b << 16);
}
// f32 -> fp8 e4m3 (OCP), HW convert (RNE+sat)
__device__ __forceinline__ unsigned char f32_to_fp8(float v) {
    int p = __builtin_amdgcn_cvt_pk_fp8_f32(v, v, 0, false);
    return (unsigned char)(p & 0xFF);
}

// async 16B global -> LDS (direct, no VGPR round-trip)
__device__ __forceinline__ void gl2lds16(const unsigned short* g, unsigned short* l) {
    __builtin_amdgcn_global_load_lds(
        (const __attribute__((address_space(1))) void*)g,
        (__attribute__((address_space(3))) void*)l, 16, 0, 0);
}

// ---------------- merged prologue: W->bf16 frag-major, bounds, sums, deg_count ----

__device__ __forceinline__ void wconv_one(const float* __restrict__ W,
                                          unsigned short* __restrict__ Bh, int i) {
    int k = i >> 8, c = i & 255;
    size_t pos = (size_t)(k >> 5) * 8192 + (size_t)(((c >> 4) * 4 + ((k >> 3) & 3)) * 128 + (c & 15) * 8 + (k & 7));
    Bh[pos] = bf16rne(W[i]);
}

__global__ __launch_bounds__(256)
void k_prep(const float* __restrict__ W1, unsigned short* __restrict__ Bh1,
            const float* __restrict__ W2, unsigned short* __restrict__ Bh2,
            const int* __restrict__ batch, int* __restrict__ bounds, float* __restrict__ sums,
            const int* __restrict__ dst, int* __restrict__ deg_i) {
    const int T = gridDim.x * 256;
    const int gid = blockIdx.x * 256 + threadIdx.x;
    for (int i = gid; i < IN_DIM * 256; i += T) wconv_one(W1, Bh1, i);
    for (int i = gid; i < HID_DIM * 256; i += T) wconv_one(W2, Bh2, i);
    for (int i = gid; i < N_GRAPHS * HID_DIM; i += T) sums[i] = 0.f;
    if (gid <= N_GRAPHS) {
        int lo = 0, hi = N_NODES;
        while (lo < hi) {
            int mid = (lo + hi) >> 1;
            if (batch[mid] < gid) lo = mid + 1; else hi = mid;
        }
        bounds[gid] = lo;
    }
    for (int e = gid; e < N_EDGES; e += T) atomicAdd(&deg_i[dst[e]], 1);
}

#define SCAN_BLK 1024
#define SCAN_NBLK ((N_NODES + SCAN_BLK - 1) / SCAN_BLK)  // 49

__global__ __launch_bounds__(SCAN_BLK)
void k_scan_blk(const int* __restrict__ deg, int* __restrict__ row_start,
                float* __restrict__ dinv, int* __restrict__ blk_tot) {
    __shared__ int tmp[SCAN_BLK];
    int t = threadIdx.x;
    int i = blockIdx.x * SCAN_BLK + t;
    int d = 0;
    if (i < N_NODES) {
        d = deg[i];
        dinv[i] = rsqrtf((float)d + 1.0f);
    }
    tmp[t] = d;
    __syncthreads();
    #pragma unroll
    for (int off = 1; off < SCAN_BLK; off <<= 1) {
        int v = (t >= off) ? tmp[t - off] : 0;
        __syncthreads();
        tmp[t] += v;
        __syncthreads();
    }
    if (i < N_NODES) row_start[i] = tmp[t] - d;
    if (t == SCAN_BLK - 1) blk_tot[blockIdx.x] = tmp[t];
}

__global__ __launch_bounds__(SCAN_BLK)
void k_scan_add(int* __restrict__ row_start, const int* __restrict__ blk_tot) {
    __shared__ int soff;
    int t = threadIdx.x;
    int bid = blockIdx.x;
    if (t < 64) {
        int v = (t < bid) ? blk_tot[t] : 0;
        #pragma unroll
        for (int m = 1; m < 64; m <<= 1) v += __shfl_xor(v, m, 64);
        if (t == 0) soff = v;
    }
    __syncthreads();
    int i = bid * SCAN_BLK + t;
    if (i < N_NODES) row_start[i] += soff;
    if (bid == 0 && t == 0) row_start[N_NODES] = N_EDGES;
}

// xf8[n,c] = fp8(x[n,c] * dinv[n] * 8)   (pre-scaled gather plane for layer 1)
__global__ __launch_bounds__(256)
void k_x2f8(const float* __restrict__ x, const float* __restrict__ dinv,
            unsigned char* __restrict__ xf8) {
    int i = blockIdx.x * blockDim.x + threadIdx.x;  // uint granule (4 ch)
    if (i >= N_NODES * IN_DIM / 4) return;
    float4 v = ((const float4*)x)[i];
    float s = dinv[i >> 5] * 8.f;
    unsigned int lo = (unsigned int)__builtin_amdgcn_cvt_pk_fp8_f32(v.x * s, v.y * s, 0, false) & 0xFFFFu;
    unsigned int hi = (unsigned int)__builtin_amdgcn_cvt_pk_fp8_f32(v.z * s, v.w * s, 0, false) & 0xFFFFu;
    ((unsigned int*)xf8)[i] = lo | (hi << 16);
}

__global__ void k_csr_fill(const int* __restrict__ src, const int* __restrict__ dst,
                           const int* __restrict__ row_start, int* __restrict__ cursor,
                           int* __restrict__ col) {
    int e = blockIdx.x * blockDim.x + threadIdx.x;
    if (e < N_EDGES) {
        int d = dst[e];
        int pos = atomicAdd(&cursor[d], 1);
        col[row_start[d] + pos] = src[e];
    }
}

// ---------------- MFMA GEMM (unchanged from round 16) ----------------

template<int MODE>
__global__ __launch_bounds__(256)
void k_gemm_mfma(const unsigned short* __restrict__ Ah,
                 const unsigned short* __restrict__ Bh,
                 const float* __restrict__ dinv, const float* __restrict__ bias,
                 unsigned short* __restrict__ Cbf, unsigned char* __restrict__ Cf8,
                 int M, int K) {
    __shared__ unsigned short AhL[2][2][2048];

    const int tid = threadIdx.x;
    const int wv = tid >> 6, lane = tid & 63;
    const int m0 = blockIdx.x * 64;

    const int ar = wv * 16 + (lane & 15);
    const int kseg = lane >> 4;
    const unsigned short* aph = Ah + (size_t)(m0 + ar) * K + kseg * 8;
    const int adoff = (wv * 64 + lane) * 8;

    f4 acc[4][4];
    #pragma unroll
    for (int mi = 0; mi < 4; ++mi)
        #pragma unroll
        for (int nj = 0; nj < 4; ++nj)
            acc[mi][nj] = f4{0.f, 0.f, 0.f, 0.f};

    const int nsteps = K >> 6;
    gl2lds16(aph, &AhL[0][0][adoff]);
    gl2lds16(aph + 32, &AhL[0][1][adoff]);

    int cur = 0;
    for (int s = 0; s < nsteps; ++s) {
        __syncthreads();
        if (s + 1 < nsteps) {
            gl2lds16(aph + (s + 1) * 64, &AhL[cur ^ 1][0][adoff]);
            gl2lds16(aph + (s + 1) * 64 + 32, &AhL[cur ^ 1][1][adoff]);
        }
        #pragma unroll
        for (int kk = 0; kk < 2; ++kk) {
            const int bstep = s * 2 + kk;
            const unsigned short* gb = Bh + (size_t)bstep * 8192 + wv * 2048 + lane * 8;
            sh8 bfh[4];
            #pragma unroll
            for (int nj = 0; nj < 4; ++nj)
                bfh[nj] = *reinterpret_cast<const sh8*>(gb + nj * 512);
            sh8 afh[4];
            #pragma unroll
            for (int mi = 0; mi < 4; ++mi)
                afh[mi] = *reinterpret_cast<const sh8*>(&AhL[cur][kk][mi * 512 + lane * 8]);
            #pragma unroll
            for (int mi = 0; mi < 4; ++mi)
                #pragma unroll
                for (int nj = 0; nj < 4; ++nj)
                    acc[mi][nj] = __builtin_amdgcn_mfma_f32_16x16x32_bf16(afh[mi], bfh[nj], acc[mi][nj], 0, 0, 0);
        }
        cur ^= 1;
    }

    #pragma unroll
    for (int mi = 0; mi < 4; ++mi) {
        #pragma unroll
        for (int q = 0; q < 4; ++q) {
            int grow = m0 + mi * 16 + (lane >> 4) * 4 + q;
            if (grow < M) {
                float dm16 = (MODE == 0) ? dinv[grow] * 16.f : 0.f;
                #pragma unroll
                for (int nj = 0; nj < 4; ++nj) {
                    int gcol = wv * 64 + nj * 16 + (lane & 15);
                    float v = acc[mi][nj][q];
                    if (MODE == 0) {
                        Cf8[(size_t)grow * 256 + gcol] = f32_to_fp8(v * dm16);
                    } else {
                        Cbf[(size_t)grow * 256 + gcol] = bf16rne(fmaxf(v + bias[gcol], 0.f));
                    }
                }
            }
        }
    }
}

// ---------------- aggregation ----------------

// layer-1: z[n] = dinv[n] * ( dinv[n]*x[n] + (1/8) * sum xf8[s] )
// xf8 pre-scaled by dinv[src]*8. Half-wave dual-edge + 8x unroll (uint gathers).
__global__ __launch_bounds__(256)
void k_agg_x(const float* __restrict__ x, const unsigned char* __restrict__ xf8,
             const int* __restrict__ row_start, const int* __restrict__ col,
             const float* __restrict__ dinv, unsigned short* __restrict__ zh) {
    int wv = threadIdx.x >> 6, lane = threadIdx.x & 63;
    int half = lane >> 5, sub = lane & 31;
    int n = blockIdx.x * 4 + wv;

    float a0 = 0.f, a1 = 0.f, a2 = 0.f, a3 = 0.f;
    float dn = dinv[n];
    if (half == 0) {
        float4 xs = ((const float4*)x)[(size_t)n * 32 + sub];
        a0 = xs.x * dn * 8.f; a1 = xs.y * dn * 8.f;
        a2 = xs.z * dn * 8.f; a3 = xs.w * dn * 8.f;
    }
    const unsigned int* xw = (const unsigned int*)xf8;   // 4 fp8 per uint
    int e = row_start[n] + half;
    const int e1 = row_start[n + 1];
    for (; e + 14 < e1; e += 16) {
        int s0 = col[e], s1 = col[e + 2], s2 = col[e + 4], s3 = col[e + 6];
        int s4 = col[e + 8], s5 = col[e + 10], s6 = col[e + 12], s7 = col[e + 14];
        unsigned int w0 = xw[(size_t)s0 * 32 + sub], w1 = xw[(size_t)s1 * 32 + sub];
        unsigned int w2 = xw[(size_t)s2 * 32 + sub], w3 = xw[(size_t)s3 * 32 + sub];
        unsigned int w4 = xw[(size_t)s4 * 32 + sub], w5 = xw[(size_t)s5 * 32 + sub];
        unsigned int w6 = xw[(size_t)s6 * 32 + sub], w7 = xw[(size_t)s7 * 32 + sub];
        #pragma unroll
        for (int k = 0; k < 8; ++k) {
            unsigned int w = (k == 0) ? w0 : (k == 1) ? w1 : (k == 2) ? w2 : (k == 3) ? w3
                           : (k == 4) ? w4 : (k == 5) ? w5 : (k == 6) ? w6 : w7;
            f2 p0 = __builtin_amdgcn_cvt_pk_f32_fp8(w, false);
            f2 p1 = __builtin_amdgcn_cvt_pk_f32_fp8(w, true);
            a0 += p0.x; a1 += p0.y; a2 += p1.x; a3 += p1.y;
        }
    }
    for (; e + 6 < e1; e += 8) {
        int s0 = col[e], s1 = col[e + 2], s2 = col[e + 4], s3 = col[e + 6];
        unsigned int w0 = xw[(size_t)s0 * 32 + sub], w1 = xw[(size_t)s1 * 32 + sub];
        unsigned int w2 = xw[(size_t)s2 * 32 + sub], w3 = xw[(size_t)s3 * 32 + sub];
        #pragma unroll
        for (int k = 0; k < 4; ++k) {
            unsigned int w = (k == 0) ? w0 : (k == 1) ? w1 : (k == 2) ? w2 : w3;
            f2 p0 = __builtin_amdgcn_cvt_pk_f32_fp8(w, false);
            f2 p1 = __builtin_amdgcn_cvt_pk_f32_fp8(w, true);
            a0 += p0.x; a1 += p0.y; a2 += p1.x; a3 += p1.y;
        }
    }
    for (; e < e1; e += 2) {
        int s = col[e];
        unsigned int w = xw[(size_t)s * 32 + sub];
        f2 p0 = __builtin_amdgcn_cvt_pk_f32_fp8(w, false);
        f2 p1 = __builtin_amdgcn_cvt_pk_f32_fp8(w, true);
        a0 += p0.x; a1 += p0.y; a2 += p1.x; a3 += p1.y;
    }
    a0 += __shfl_xor(a0, 32, 64);
    a1 += __shfl_xor(a1, 32, 64);
    a2 += __shfl_xor(a2, 32, 64);
    a3 += __shfl_xor(a3, 32, 64);
    if (half == 0) {
        float s = dn * 0.125f;   // undo x8 pre-scale
        us4 oh;
        oh.x = bf16rne(a0 * s);
        oh.y = bf16rne(a1 * s);
        oh.z = bf16rne(a2 * s);
        oh.w = bf16rne(a3 * s);
        ((us4*)zh)[(size_t)n * 32 + sub] = oh;
    }
}

// layer-2 agg + relu + mean-pool fused. yb = fp8(y2*16), pre-scaled by dinv[src].
// 8 nodes per 512-thread block. Half-wave dual-edge + 8x unroll (uint2 gathers).
__global__ __launch_bounds__(512)
void k_agg_pool(const unsigned char* __restrict__ yb, const int* __restrict__ row_start,
                const int* __restrict__ col, const float* __restrict__ dinv,
                const float* __restrict__ bias, const int* __restrict__ batch,
                float* __restrict__ sums) {
    __shared__ float lsum[8][256];
    const int tid = threadIdx.x;
    const int wv = tid >> 6, lane = tid & 63;
    const int half = lane >> 5, sub = lane & 31;
    const int base = blockIdx.x * 8;
    const int n = base + wv;

    const bool uni = (batch[base] == batch[base + 7]);

    const uint2* y8 = (const uint2*)yb;   // 8 fp8 per element
    float a[8] = {0.f, 0.f, 0.f, 0.f, 0.f, 0.f, 0.f, 0.f};
    if (half == 0) {
        uint2 w = y8[(size_t)n * 32 + sub];
        f2 p0 = __builtin_amdgcn_cvt_pk_f32_fp8(w.x, false);
        f2 p1 = __builtin_amdgcn_cvt_pk_f32_fp8(w.x, true);
        f2 p2 = __builtin_amdgcn_cvt_pk_f32_fp8(w.y, false);
        f2 p3 = __builtin_amdgcn_cvt_pk_f32_fp8(w.y, true);
        a[0] = p0.x; a[1] = p0.y; a[2] = p1.x; a[3] = p1.y;
        a[4] = p2.x; a[5] = p2.y; a[6] = p3.x; a[7] = p3.y;
    }
    int e = row_start[n] + half;
    const int e1 = row_start[n + 1];
    for (; e + 14 < e1; e += 16) {
        int s0 = col[e], s1 = col[e + 2], s2 = col[e + 4], s3 = col[e + 6];
        int s4 = col[e + 8], s5 = col[e + 10], s6 = col[e + 12], s7 = col[e + 14];
        uint2 w0 = y8[(size_t)s0 * 32 + sub], w1 = y8[(size_t)s1 * 32 + sub];
        uint2 w2 = y8[(size_t)s2 * 32 + sub], w3 = y8[(size_t)s3 * 32 + sub];
        uint2 w4 = y8[(size_t)s4 * 32 + sub], w5 = y8[(size_t)s5 * 32 + sub];
        uint2 w6 = y8[(size_t)s6 * 32 + sub], w7 = y8[(size_t)s7 * 32 + sub];
        #pragma unroll
        for (int k = 0; k < 8; ++k) {
            uint2 w = (k == 0) ? w0 : (k == 1) ? w1 : (k == 2) ? w2 : (k == 3) ? w3
                    : (k == 4) ? w4 : (k == 5) ? w5 : (k == 6) ? w6 : w7;
            f2 p0 = __builtin_amdgcn_cvt_pk_f32_fp8(w.x, false);
            f2 p1 = __builtin_amdgcn_cvt_pk_f32_fp8(w.x, true);
            f2 p2 = __builtin_amdgcn_cvt_pk_f32_fp8(w.y, false);
            f2 p3 = __builtin_amdgcn_cvt_pk_f32_fp8(w.y, true);
            a[0] += p0.x; a[1] += p0.y; a[2] += p1.x; a[3] += p1.y;
            a[4] += p2.x; a[5] += p2.y; a[6] += p3.x; a[7] += p3.y;
        }
    }
    for (; e + 6 < e1; e += 8) {
        int s0 = col[e], s1 = col[e + 2], s2 = col[e + 4], s3 = col[e + 6];
        uint2 w0 = y8[(size_t)s0 * 32 + sub], w1 = y8[(size_t)s1 * 32 + sub];
        uint2 w2 = y8[(size_t)s2 * 32 + sub], w3 = y8[(size_t)s3 * 32 + sub];
        #pragma unroll
        for (int k = 0; k < 4; ++k) {
            uint2 w = (k == 0) ? w0 : (k == 1) ? w1 : (k == 2) ? w2 : w3;
            f2 p0 = __builtin_amdgcn_cvt_pk_f32_fp8(w.x, false);
            f2 p1 = __builtin_amdgcn_cvt_pk_f32_fp8(w.x, true);
            f2 p2 = __builtin_amdgcn_cvt_pk_f32_fp8(w.y, false);
            f2 p3 = __builtin_amdgcn_cvt_pk_f32_fp8(w.y, true);
            a[0] += p0.x; a[1] += p0.y; a[2] += p1.x; a[3] += p1.y;
            a[4] += p2.x; a[5] += p2.y; a[6] += p3.x; a[7] += p3.y;
        }
    }
    for (; e < e1; e += 2) {
        int s = col[e];
        uint2 w = y8[(size_t)s * 32 + sub];
        f2 p0 = __builtin_amdgcn_cvt_pk_f32_fp8(w.x, false);
        f2 p1 = __builtin_amdgcn_cvt_pk_f32_fp8(w.x, true);
        f2 p2 = __builtin_amdgcn_cvt_pk_f32_fp8(w.y, false);
        f2 p3 = __builtin_amdgcn_cvt_pk_f32_fp8(w.y, true);
        a[0] += p0.x; a[1] += p0.y; a[2] += p1.x; a[3] += p1.y;
        a[4] += p2.x; a[5] += p2.y; a[6] += p3.x; a[7] += p3.y;
    }
    #pragma unroll
    for (int j = 0; j < 8; ++j) a[j] += __shfl_xor(a[j], 32, 64);

    if (half == 0) {
        float dn = dinv[n] * 0.0625f;   // undo x16 fp8 pre-scale
        float4 b0 = ((const float4*)bias)[sub * 2];
        float4 b1 = ((const float4*)bias)[sub * 2 + 1];
        float4 o0, o1;
        o0.x = fmaxf(a[0] * dn + b0.x, 0.f);
        o0.y = fmaxf(a[1] * dn + b0.y, 0.f);
        o0.z = fmaxf(a[2] * dn + b0.z, 0.f);
        o0.w = fmaxf(a[3] * dn + b0.w, 0.f);
        o1.x = fmaxf(a[4] * dn + b1.x, 0.f);
        o1.y = fmaxf(a[5] * dn + b1.y, 0.f);
        o1.z = fmaxf(a[6] * dn + b1.z, 0.f);
        o1.w = fmaxf(a[7] * dn + b1.w, 0.f);
        if (uni) {
            ((float4*)&lsum[wv][sub * 8])[0] = o0;
            ((float4*)&lsum[wv][sub * 8])[1] = o1;
        } else {
            int g = batch[n];
            atomicAdd(&sums[g * 256 + sub * 8 + 0], o0.x);
            atomicAdd(&sums[g * 256 + sub * 8 + 1], o0.y);
            atomicAdd(&sums[g * 256 + sub * 8 + 2], o0.z);
            atomicAdd(&sums[g * 256 + sub * 8 + 3], o0.w);
            atomicAdd(&sums[g * 256 + sub * 8 + 4], o1.x);
            atomicAdd(&sums[g * 256 + sub * 8 + 5], o1.y);
            atomicAdd(&sums[g * 256 + sub * 8 + 6], o1.z);
            atomicAdd(&sums[g * 256 + sub * 8 + 7], o1.w);
        }
    }
    __syncthreads();
    if (uni && tid < 256) {
        float v = 0.f;
        #pragma unroll
        for (int w = 0; w < 8; ++w) v += lsum[w][tid];
        atomicAdd(&sums[batch[base] * 256 + tid], v);
    }
}

// ---------------- FC ----------------

__global__ void k_final(const float* __restrict__ sums, const int* __restrict__ bounds,
                        const float* __restrict__ Wfc, const float* __restrict__ bfc,
                        float* __restrict__ out) {
    __shared__ float red[HID_DIM];
    int g = blockIdx.x;
    int c = threadIdx.x;
    float cnt = (float)(bounds[g + 1] - bounds[g]);
    float v = sums[g * HID_DIM + c] / fmaxf(cnt, 1.0f) * Wfc[c];
    red[c] = v;
    __syncthreads();
    for (int s = HID_DIM / 2; s > 0; s >>= 1) {
        if (c < s) red[c] += red[c + s];
        __syncthreads();
    }
    if (c == 0) out[g] = red[0] + bfc[0];
}

// ---------------- launch ----------------

extern "C" void kernel_launch(void* const* d_in, const int* in_sizes, int n_in,
                              void* d_out, int out_size, void* d_ws, size_t ws_size,
                              hipStream_t stream) {
    const float* x    = (const float*)d_in[0];
    const int*   ei   = (const int*)d_in[1];
    const int*   batch= (const int*)d_in[2];
    const float* W1   = (const float*)d_in[3];
    const float* b1   = (const float*)d_in[4];
    const float* W2   = (const float*)d_in[5];
    const float* b2   = (const float*)d_in[6];
    const float* Wfc  = (const float*)d_in[7];
    const float* bfc  = (const float*)d_in[8];
    float* out = (float*)d_out;

    const int* src = ei;
    const int* dst = ei + N_EDGES;

    char* ws = (char*)d_ws;
    const size_t PLANE256 = (size_t)M_PAD * 256 * 2;
    size_t off = 0;
    unsigned short* h1h = (unsigned short*)(ws + off); off += PLANE256;
    char*           r1  = (char*)(ws + off); off += PLANE256;  // zh then y2f8
    unsigned char*  xf8 = (unsigned char*)(ws + off); off += (size_t)N_NODES * 128;
    int*   deg_i     = (int*)  (ws + off); off += 200704;
    int*   cursor    = (int*)  (ws + off); off += 200704;
    float* dinv      = (float*)(ws + off); off += 200704;
    int*   row_start = (int*)  (ws + off); off += 200704;
    int*   col       = (int*)  (ws + off); off += (size_t)N_EDGES * 4;
    unsigned short* Bh1 = (unsigned short*)(ws + off); off += 65536;
    unsigned short* Bh2 = (unsigned short*)(ws + off); off += 131072;
    float* sums      = (float*)(ws + off); off += 65536;
    int*   bounds    = (int*)  (ws + off); off += 512;
    int*   blk_tot   = (int*)  (ws + off); off += 512;
    (void)ws_size; (void)in_sizes; (void)n_in; (void)out_size;

    unsigned short* zh   = (unsigned short*)r1;  // [M_PAD,128] bf16, dead after GEMM1
    unsigned char*  y2f8 = (unsigned char*)r1;   // [M_PAD,256] fp8, written by GEMM2

    // 1. zero counters + merged prologue (W conv, bounds, sums, deg_count) + CSR
    hipMemsetAsync(deg_i, 0, 2 * 200704, stream);  // deg_i + cursor (adjacent)
    k_prep<<<2048, 256, 0, stream>>>(W1, Bh1, W2, Bh2, batch, bounds, sums, dst, deg_i);
    k_scan_blk<<<SCAN_NBLK, SCAN_BLK, 0, stream>>>(deg_i, row_start, dinv, blk_tot);
    k_scan_add<<<SCAN_NBLK, SCAN_BLK, 0, stream>>>(row_start, blk_tot);
    k_x2f8<<<(N_NODES * IN_DIM / 4 + 255) / 256, 256, 0, stream>>>(x, dinv, xf8);
    k_csr_fill<<<(N_EDGES + 255) / 256, 256, 0, stream>>>(src, dst, row_start, cursor, col);

    const int gemm_grid = (N_NODES + 63) / 64;  // 782

    // 2. layer 1: zh = bf16(A_hat @ x) ; h1h = bf16(relu(z @ W1 + b1))
    k_agg_x<<<N_NODES / 4, 256, 0, stream>>>(x, xf8, row_start, col, dinv, zh);
    k_gemm_mfma<1><<<gemm_grid, 256, 0, stream>>>(zh, Bh1, dinv, b1, h1h, nullptr, N_NODES, IN_DIM);

    // 3. layer 2: y2f8 = fp8((h1 @ W2) * dinv * 16) ; fused agg+relu+pool
    k_gemm_mfma<0><<<gemm_grid, 256, 0, stream>>>(h1h, Bh2, dinv, b2, nullptr, y2f8, N_NODES, HID_DIM);
    k_agg_pool<<<N_NODES / 8, 512, 0, stream>>>(y2f8, row_start, col, dinv, b2, batch, sums);

    // 4. fc
    k_final<<<N_GRAPHS, HID_DIM, 0, stream>>>(sums, bounds, Wfc, bfc, out);
}